// Round 7
// baseline (6218.616 us; speedup 1.0000x reference)
//
#include <hip/hip_runtime.h>
#include <math.h>

#define N0   17186
#define FIN  6
#define H1C  64
#define H2C  32
#define KSEL 12031
#define BATCH 64
#define NE   500000
#define NT   (BATCH * N0)

typedef unsigned int uint;
typedef unsigned char uchar;

__device__ __forceinline__ uint keyOf(float f) {
    uint u = __float_as_uint(f);
    return (u & 0x80000000u) ? ~u : (u | 0x80000000u);
}

// ---------- edge dtype detection / normalization ----------
__global__ void k_detect(const uint* ei, int* flag64) {
    __shared__ int any;
    if (threadIdx.x == 0) any = 0;
    __syncthreads();
    for (int i = threadIdx.x; i < 1024; i += blockDim.x)
        if (ei[2 * i + 1] != 0u) any = 1;
    __syncthreads();
    if (threadIdx.x == 0) *flag64 = any ? 0 : 1;
}

__global__ void k_convert(const void* ei, const int* flag64, int* src, int* dst) {
    int f = *flag64;
    int stride = gridDim.x * blockDim.x;
    for (int i = blockIdx.x * blockDim.x + threadIdx.x; i < 2 * NE; i += stride) {
        int v = f ? (int)((const long long*)ei)[i] : ((const int*)ei)[i];
        if (i < NE) src[i] = v; else dst[i - NE] = v;
    }
}

// ---------- CSR build ----------
__global__ void k_deg(const int* dst, uint* deg) {
    int e = blockIdx.x * blockDim.x + threadIdx.x;
    if (e < NE) atomicAdd(&deg[dst[e]], 1u);
}

__global__ void k_scan(const uint* deg, int* rowptr) {
    __shared__ uint tsum[256];
    int tid = threadIdx.x;
    const int CH = (N0 + 255) / 256;  // 68
    int beg = tid * CH, end = beg + CH;
    if (end > N0) end = N0;
    uint s = 0;
    for (int i = beg; i < end; i++) s += deg[i];
    tsum[tid] = s;
    __syncthreads();
    for (int off = 1; off < 256; off <<= 1) {
        uint v = tsum[tid];
        uint a = (tid >= off) ? tsum[tid - off] : 0u;
        __syncthreads();
        tsum[tid] = v + a;
        __syncthreads();
    }
    uint run = (tid > 0) ? tsum[tid - 1] : 0u;
    for (int i = beg; i < end; i++) { rowptr[i] = (int)run; run += deg[i]; }
    if (tid == 255) rowptr[N0] = (int)run;
}

__global__ void k_scatter(const int* src, const int* dst, const int* rowptr,
                          uint* cnt, int* csr) {
    int e = blockIdx.x * blockDim.x + threadIdx.x;
    if (e < NE) {
        int d = dst[e];
        uint p = atomicAdd(&cnt[d], 1u);
        csr[rowptr[d] + (int)p] = src[e];
    }
}

// ---------- conv1 (graph 0) ----------
__global__ void k_xw1(const float* x, const float* W1, float* xw1) {
    int t = blockIdx.x * blockDim.x + threadIdx.x;
    if (t >= N0 * H1C) return;
    int i = t >> 6, h = t & 63;
    float acc = 0.f;
#pragma unroll
    for (int f = 0; f < FIN; f++) acc += x[i * FIN + f] * W1[f * H1C + h];
    xw1[t] = acc;
}

__global__ void k_dinv(const uint* deg, float* dinv) {
    int i = blockIdx.x * blockDim.x + threadIdx.x;
    if (i < N0) dinv[i] = rsqrtf(1.0f + (float)deg[i]);
}

// gather conv1 messages + finish h1 (fused fin1), 4-way unrolled
__global__ void k_gath1(const int* rowptr, const int* csr, const float* dinv,
                        const float* xw1, const float* b1, float* h1) {
    int wid = (blockIdx.x * blockDim.x + threadIdx.x) >> 6;
    int lane = threadIdx.x & 63;
    if (wid >= N0) return;
    int d = wid;
    int beg = rowptr[d], end = rowptr[d + 1];
    float a0 = 0.f, a1 = 0.f, a2 = 0.f, a3 = 0.f;
    int e = beg;
    for (; e + 4 <= end; e += 4) {
        int s0 = csr[e], s1 = csr[e + 1], s2 = csr[e + 2], s3 = csr[e + 3];
        a0 += xw1[(size_t)s0 * H1C + lane] * dinv[s0];
        a1 += xw1[(size_t)s1 * H1C + lane] * dinv[s1];
        a2 += xw1[(size_t)s2 * H1C + lane] * dinv[s2];
        a3 += xw1[(size_t)s3 * H1C + lane] * dinv[s3];
    }
    for (; e < end; e++) {
        int s = csr[e];
        a0 += xw1[(size_t)s * H1C + lane] * dinv[s];
    }
    float acc = (a0 + a1) + (a2 + a3);
    float did = dinv[d];
    float v = acc * did + xw1[(size_t)d * H1C + lane] * did * did + b1[lane];
    h1[(size_t)d * H1C + lane] = fmaxf(v, 0.f);
}

// ---------- pooling score ----------
__global__ void k_h1w(const float* h1, const float* Wp, float* h1w) {
    int i = blockIdx.x * blockDim.x + threadIdx.x;
    if (i >= N0) return;
    const float* row = h1 + (size_t)i * H1C;
    float acc = 0.f;
#pragma unroll
    for (int h = 0; h < H1C; h++) acc += row[h] * Wp[h];
    h1w[i] = acc;
}

// graph-0 score: gather + self-loop (fused smsg+score0)
__global__ void k_gscore0(const int* rowptr, const int* csr, const float* dinv,
                          const float* h1w, const float* bp, float* score) {
    int d = blockIdx.x * blockDim.x + threadIdx.x;
    if (d >= N0) return;
    float acc = 0.f;
    int beg = rowptr[d], end = rowptr[d + 1];
    for (int e = beg; e < end; e++) {
        int s = csr[e];
        acc += h1w[s] * dinv[s];
    }
    float did = dinv[d];
    score[d] = acc * did + h1w[d] * did * did + bp[0];
}

// graphs 1..63: score = relu(x@W1+b1) . Wp + bp
// Weights staged in LDS: sW[h*8] = {W1[0..5][h], b1[h], Wp[h]} -> per h-step
// two broadcast ds_read_b128 with immediate offsets (no per-load VALU).
__global__ void k_score_rest(const float* __restrict__ x, const float* __restrict__ W1,
                             const float* __restrict__ b1, const float* __restrict__ Wp,
                             const float* __restrict__ bp, float* score) {
    __shared__ float sW[H1C * 8];
    int tid = threadIdx.x;
    if (tid < H1C) {
#pragma unroll
        for (int f = 0; f < FIN; f++) sW[tid * 8 + f] = W1[f * H1C + tid];
        sW[tid * 8 + 6] = b1[tid];
        sW[tid * 8 + 7] = Wp[tid];
    }
    __syncthreads();
    int idx = blockIdx.x * blockDim.x + tid;
    int n = N0 + idx;
    if (n >= NT) return;
    const float2* xv = reinterpret_cast<const float2*>(x) + (size_t)n * 3;
    float2 x01 = xv[0], x23 = xv[1], x45 = xv[2];
    float sc = bp[0];
#pragma unroll
    for (int h = 0; h < H1C; h++) {
        float4 wa = *reinterpret_cast<const float4*>(&sW[h * 8]);
        float4 wb = *reinterpret_cast<const float4*>(&sW[h * 8 + 4]);
        float a = wb.z;                       // b1[h]
        a += x01.x * wa.x; a += x01.y * wa.y;
        a += x23.x * wa.z; a += x23.y * wa.w;
        a += x45.x * wb.x; a += x45.y * wb.y;
        sc += fmaxf(a, 0.f) * wb.w;           // Wp[h]
    }
    score[n] = sc;
}

// ---------- per-graph top-K selection (radix select on float keys) ----------
__global__ void k_topk(const float* score, uchar* sel) {
    int g = blockIdx.x;
    const float* sc = score + (size_t)g * N0;
    uchar* sl = sel + (size_t)g * N0;
    __shared__ uint hist[4][256];
    __shared__ uint shPrefix, shWant;
    __shared__ uint wtot[4];
    int tid = threadIdx.x;
    int wave = tid >> 6, lane = tid & 63;
    uint prefix = 0, want = KSEL;
    for (int pass = 0; pass < 4; pass++) {
        int shift = 24 - 8 * pass;
#pragma unroll
        for (int w = 0; w < 4; w++) hist[w][tid] = 0;
        __syncthreads();
        for (int i = tid; i < N0; i += 256) {
            uint k = keyOf(sc[i]);
            bool active = (pass == 0) || ((k >> (shift + 8)) == prefix);
            if (active) atomicAdd(&hist[wave][(k >> shift) & 255], 1u);
        }
        __syncthreads();
        uint merged = hist[0][tid] + hist[1][tid] + hist[2][tid] + hist[3][tid];
        hist[0][tid] = merged;
        __syncthreads();
        if (tid == 0) {
            uint cum = 0; int d = 255;
            for (; d > 0; d--) { cum += hist[0][d]; if (cum >= want) break; }
            if (cum < want) cum += hist[0][0];        // d==0 fallthrough
            shWant = want - (cum - hist[0][d]);
            shPrefix = (prefix << 8) | (uint)d;
        }
        __syncthreads();
        prefix = shPrefix; want = shWant;
        __syncthreads();
    }
    uint T = prefix, needEq = want;
    uint runningEq = 0;
    for (int base = 0; base < N0; base += 256) {
        int i = base + tid;
        uint k = (i < N0) ? keyOf(sc[i]) : 0u;
        bool isEq = (i < N0) && (k == T);
        unsigned long long mask = __ballot(isEq);
        uint wprefix = (uint)__popcll(mask & ((1ull << lane) - 1ull));
        uint wcount = (uint)__popcll(mask);
        if (lane == 0) wtot[wave] = wcount;
        __syncthreads();
        uint before = 0;
#pragma unroll
        for (int w = 0; w < 4; w++) if (w < wave) before += wtot[w];
        uint total = wtot[0] + wtot[1] + wtot[2] + wtot[3];
        if (i < N0) {
            uchar s = 0;
            if (k > T) s = 1;
            else if (isEq && (runningEq + before + wprefix) < needEq) s = 1;
            sl[i] = s;
        }
        runningEq += total;
        __syncthreads();
    }
}

// ---------- conv2 (graph 0, selection-filtered) ----------
__global__ void k_gdinv2(const int* rowptr, const int* csr, const uchar* sel,
                         float* dinv2) {
    int d = blockIdx.x * blockDim.x + threadIdx.x;
    if (d >= N0) return;
    float r = 0.f;
    if (sel[d]) {
        int c = 0;
        int beg = rowptr[d], end = rowptr[d + 1];
        for (int e = beg; e < end; e++) c += sel[csr[e]];
        r = rsqrtf(1.f + (float)c);
    }
    dinv2[d] = r;
}

__global__ void k_xw2(const float* h1, const float* score, const uchar* sel,
                      const float* W2, float* xw2) {
    int gt = blockIdx.x * blockDim.x + threadIdx.x;
    int i = gt >> 5, c = gt & 31;
    if (i >= N0) return;
    if (!sel[i]) return;
    float t = tanhf(score[i]);
    const float* row = h1 + (size_t)i * H1C;
    float acc = 0.f;
#pragma unroll
    for (int h = 0; h < H1C; h++) acc += row[h] * W2[h * H2C + c];
    xw2[i * H2C + c] = acc * t;
}

__global__ void k_gath2(const int* rowptr, const int* csr, const uchar* sel,
                        const float* dinv2, const float* xw2, float* acc2) {
    int wid = (blockIdx.x * blockDim.x + threadIdx.x) >> 6;
    int lane = threadIdx.x & 63;
    if (wid >= N0) return;
    int d = wid;
    if (!sel[d]) return;
    int c = lane & 31;
    int beg = rowptr[d], end = rowptr[d + 1];
    float a0 = 0.f, a1 = 0.f;
    int e = beg + (lane >> 5);
    for (; e + 2 < end; e += 4) {   // this half-wave handles e, e+2
        int s0 = csr[e], s1 = csr[e + 2];
        a0 += xw2[(size_t)s0 * H2C + c] * dinv2[s0];
        a1 += xw2[(size_t)s1 * H2C + c] * dinv2[s1];
    }
    if (e < end) {
        int s = csr[e];
        a0 += xw2[(size_t)s * H2C + c] * dinv2[s];
    }
    float acc = a0 + a1;
    acc += __shfl_xor(acc, 32, 64);
    if (lane < 32) acc2[(size_t)d * H2C + c] = acc * dinv2[d];
}

__global__ void k_fin2(const float* acc2, const float* xw2, const float* dinv2,
                       const uchar* sel, const float* b2, float* gmax) {
    __shared__ float m[32];
    int tid = threadIdx.x;
    if (tid < 32) m[tid] = 0.f;
    __syncthreads();
    int i = blockIdx.x * 8 + (tid >> 5);
    int c = tid & 31;
    float v = 0.f;
    if (i < N0 && sel[i]) {
        float di = dinv2[i];
        v = fmaxf(acc2[(size_t)i * H2C + c] + xw2[(size_t)i * H2C + c] * di * di + b2[c], 0.f);
    }
    atomicMax((int*)&m[c], __float_as_int(v));
    __syncthreads();
    if (tid < 32) atomicMax((int*)&gmax[tid], __float_as_int(m[tid]));
}

// ---------- graphs 1..63: h2 + max pool ----------
// LDS-staged weights: sW1[h*8]={W1col(6),b1,0} (2x ds_read_b128 per h),
// sW2[h*32+c] (4x ds_read_b128 per 16-chunk). Broadcast reads, immediate
// offsets -> no per-load VALU/VMEM. Chunked acc[16] (R6: spill-free, 48 VGPR).
#define BPGR 68
#define CCH 16
__global__ void k_rest_pool(const float* __restrict__ x, const float* __restrict__ score,
                            const uchar* __restrict__ sel,
                            const float* __restrict__ W1, const float* __restrict__ b1,
                            const float* __restrict__ W2, const float* __restrict__ b2,
                            float* gmax) {
    __shared__ float sW1[H1C * 8];
    __shared__ float sW2[H1C * H2C];
    __shared__ float m[H2C];
    int tid = threadIdx.x;
    if (tid < H2C) m[tid] = 0.f;
    if (tid < H1C) {
#pragma unroll
        for (int f = 0; f < FIN; f++) sW1[tid * 8 + f] = W1[f * H1C + tid];
        sW1[tid * 8 + 6] = b1[tid];
        sW1[tid * 8 + 7] = 0.f;
    }
    for (int i = tid; i < H1C * H2C; i += 256) sW2[i] = W2[i];
    __syncthreads();

    int lane = tid & 63;
    int g = blockIdx.x / BPGR + 1;
    int wslot = (blockIdx.x % BPGR) * 4 + (tid >> 6);
    int li = wslot * 64 + lane;
    bool inb = li < N0;
    int n = inb ? (g * N0 + li) : 0;
    bool valid = inb && sel[n];
    float2 x01 = {0.f, 0.f}, x23 = {0.f, 0.f}, x45 = {0.f, 0.f};
    if (valid) {
        const float2* xv = reinterpret_cast<const float2*>(x) + (size_t)n * 3;
        x01 = xv[0]; x23 = xv[1]; x45 = xv[2];
    }
    float t = valid ? tanhf(score[n]) : 0.f;
#pragma unroll 1
    for (int cc = 0; cc < H2C; cc += CCH) {
        float acc[CCH];
#pragma unroll
        for (int j = 0; j < CCH; j++) acc[j] = 0.f;
#pragma unroll
        for (int h = 0; h < H1C; h++) {
            float4 wa = *reinterpret_cast<const float4*>(&sW1[h * 8]);
            float4 wb = *reinterpret_cast<const float4*>(&sW1[h * 8 + 4]);
            float a = wb.z;                    // b1[h]
            a += x01.x * wa.x; a += x01.y * wa.y;
            a += x23.x * wa.z; a += x23.y * wa.w;
            a += x45.x * wb.x; a += x45.y * wb.y;
            float hv = fmaxf(a, 0.f);
            const float* w2r = &sW2[h * H2C + cc];
#pragma unroll
            for (int q = 0; q < CCH / 4; q++) {
                float4 w = *reinterpret_cast<const float4*>(w2r + q * 4);
                acc[q * 4 + 0] += hv * w.x;
                acc[q * 4 + 1] += hv * w.y;
                acc[q * 4 + 2] += hv * w.z;
                acc[q * 4 + 3] += hv * w.w;
            }
        }
#pragma unroll
        for (int j = 0; j < CCH; j++) {
            float v = valid ? fmaxf(t * acc[j] + b2[cc + j], 0.f) : 0.f;
#pragma unroll
            for (int o = 32; o > 0; o >>= 1) v = fmaxf(v, __shfl_xor(v, o, 64));
            if (lane == 0) atomicMax((int*)&m[cc + j], __float_as_int(v));
        }
    }
    __syncthreads();
    if (tid < H2C) atomicMax((int*)&gmax[g * H2C + tid], __float_as_int(m[tid]));
}

// ---------- readout ----------
__global__ void k_final(const float* gmax, const float* Wf, const float* bf, float* out) {
    int g = threadIdx.x;
    if (g < BATCH) {
        float acc = bf[0];
        for (int c = 0; c < H2C; c++) acc += gmax[g * H2C + c] * Wf[c];
        out[g] = 1.f / (1.f + expf(-acc));
    }
}

extern "C" void kernel_launch(void* const* d_in, const int* in_sizes, int n_in,
                              void* d_out, int out_size, void* d_ws, size_t ws_size,
                              hipStream_t stream) {
    const float* data = (const float*)d_in[0];
    const void*  ei   = d_in[1];
    const float* W1   = (const float*)d_in[2];
    const float* b1   = (const float*)d_in[3];
    const float* Wp   = (const float*)d_in[4];
    const float* bp   = (const float*)d_in[5];
    const float* W2   = (const float*)d_in[6];
    const float* b2   = (const float*)d_in[7];
    const float* Wf   = (const float*)d_in[8];
    const float* bf   = (const float*)d_in[9];
    float* out = (float*)d_out;

    char* ws = (char*)d_ws;
    size_t off = 0;
    auto A = [&](size_t bytes) -> size_t {
        size_t o = off; off += (bytes + 511) & ~(size_t)511; return o;
    };
    // zero-initialized region (single memset)
    size_t o_deg0 = A((size_t)N0 * 4);
    size_t o_cnt  = A((size_t)N0 * 4);
    size_t o_gmax = A((size_t)BATCH * H2C * 4);
    size_t zbytes = off;
    // rest
    size_t o_src  = A((size_t)NE * 4);
    size_t o_dst  = A((size_t)NE * 4);
    size_t o_rp   = A((size_t)(N0 + 1) * 4);
    size_t o_csr  = A((size_t)NE * 4);
    size_t o_xw1  = A((size_t)N0 * H1C * 4);
    size_t o_h1   = A((size_t)N0 * H1C * 4);
    size_t o_di0  = A((size_t)N0 * 4);
    size_t o_di2  = A((size_t)N0 * 4);
    size_t o_h1w  = A((size_t)N0 * 4);
    size_t o_scr  = A((size_t)NT * 4);
    size_t o_sel  = A((size_t)NT);
    size_t o_xw2  = A((size_t)N0 * H2C * 4);
    size_t o_acc2 = A((size_t)N0 * H2C * 4);
    size_t o_flag = A(4);

    uint*  deg0 = (uint*)(ws + o_deg0);
    uint*  cnt  = (uint*)(ws + o_cnt);
    float* gmax = (float*)(ws + o_gmax);
    int*   src  = (int*)(ws + o_src);
    int*   dst  = (int*)(ws + o_dst);
    int*   rp   = (int*)(ws + o_rp);
    int*   csr  = (int*)(ws + o_csr);
    float* xw1  = (float*)(ws + o_xw1);
    float* h1   = (float*)(ws + o_h1);
    float* di0  = (float*)(ws + o_di0);
    float* di2  = (float*)(ws + o_di2);
    float* h1w  = (float*)(ws + o_h1w);
    float* scr  = (float*)(ws + o_scr);
    uchar* sel  = (uchar*)(ws + o_sel);
    float* xw2  = (float*)(ws + o_xw2);
    float* acc2 = (float*)(ws + o_acc2);
    int*   flag = (int*)(ws + o_flag);

    hipMemsetAsync(ws, 0, zbytes, stream);

    k_detect<<<1, 256, 0, stream>>>((const uint*)ei, flag);
    k_convert<<<2048, 256, 0, stream>>>(ei, flag, src, dst);
    k_deg<<<(NE + 255) / 256, 256, 0, stream>>>(dst, deg0);
    k_scan<<<1, 256, 0, stream>>>(deg0, rp);
    k_scatter<<<(NE + 255) / 256, 256, 0, stream>>>(src, dst, rp, cnt, csr);
    k_xw1<<<(N0 * H1C + 255) / 256, 256, 0, stream>>>(data, W1, xw1);
    k_dinv<<<(N0 + 255) / 256, 256, 0, stream>>>(deg0, di0);
    k_gath1<<<(N0 * 64 + 255) / 256, 256, 0, stream>>>(rp, csr, di0, xw1, b1, h1);
    k_h1w<<<(N0 + 255) / 256, 256, 0, stream>>>(h1, Wp, h1w);
    k_gscore0<<<(N0 + 255) / 256, 256, 0, stream>>>(rp, csr, di0, h1w, bp, scr);
    k_score_rest<<<(NT - N0 + 255) / 256, 256, 0, stream>>>(data, W1, b1, Wp, bp, scr);
    k_topk<<<BATCH, 256, 0, stream>>>(scr, sel);
    k_gdinv2<<<(N0 + 255) / 256, 256, 0, stream>>>(rp, csr, sel, di2);
    k_xw2<<<(N0 * H2C + 255) / 256, 256, 0, stream>>>(h1, scr, sel, W2, xw2);
    k_gath2<<<(N0 * 64 + 255) / 256, 256, 0, stream>>>(rp, csr, sel, di2, xw2, acc2);
    k_fin2<<<(N0 + 7) / 8, 256, 0, stream>>>(acc2, xw2, di2, sel, b2, gmax);
    k_rest_pool<<<(BATCH - 1) * BPGR, 256, 0, stream>>>(data, scr, sel, W1, b1, W2, b2, gmax);
    k_final<<<1, 64, 0, stream>>>(gmax, Wf, bf, out);
}

// Round 8
// 547.109 us; speedup vs baseline: 11.3663x; 11.3663x over previous
//
#include <hip/hip_runtime.h>
#include <hip/hip_bf16.h>
#include <math.h>

#define N0   17186
#define FIN  6
#define H1C  64
#define H2C  32
#define KSEL 12031
#define BATCH 64
#define NE   500000
#define NT   (BATCH * N0)

typedef unsigned int uint;
typedef unsigned char uchar;
typedef __attribute__((ext_vector_type(8))) short bf16x8;
typedef __attribute__((ext_vector_type(4))) float f32x4;

__device__ __forceinline__ uint keyOf(float f) {
    uint u = __float_as_uint(f);
    return (u & 0x80000000u) ? ~u : (u | 0x80000000u);
}

__device__ __forceinline__ short f2bf(float f) {
    union { __hip_bfloat16 b; short s; } u;
    u.b = __float2bfloat16(f);
    return u.s;
}

// ---------- edge dtype detection / normalization ----------
__global__ void k_detect(const uint* ei, int* flag64) {
    __shared__ int any;
    if (threadIdx.x == 0) any = 0;
    __syncthreads();
    for (int i = threadIdx.x; i < 1024; i += blockDim.x)
        if (ei[2 * i + 1] != 0u) any = 1;
    __syncthreads();
    if (threadIdx.x == 0) *flag64 = any ? 0 : 1;
}

__global__ void k_convert(const void* ei, const int* flag64, int* src, int* dst) {
    int f = *flag64;
    int stride = gridDim.x * blockDim.x;
    for (int i = blockIdx.x * blockDim.x + threadIdx.x; i < 2 * NE; i += stride) {
        int v = f ? (int)((const long long*)ei)[i] : ((const int*)ei)[i];
        if (i < NE) src[i] = v; else dst[i - NE] = v;
    }
}

// ---------- CSR build ----------
__global__ void k_deg(const int* dst, uint* deg) {
    int e = blockIdx.x * blockDim.x + threadIdx.x;
    if (e < NE) atomicAdd(&deg[dst[e]], 1u);
}

__global__ void k_scan(const uint* deg, int* rowptr) {
    __shared__ uint tsum[256];
    int tid = threadIdx.x;
    const int CH = (N0 + 255) / 256;  // 68
    int beg = tid * CH, end = beg + CH;
    if (end > N0) end = N0;
    uint s = 0;
    for (int i = beg; i < end; i++) s += deg[i];
    tsum[tid] = s;
    __syncthreads();
    for (int off = 1; off < 256; off <<= 1) {
        uint v = tsum[tid];
        uint a = (tid >= off) ? tsum[tid - off] : 0u;
        __syncthreads();
        tsum[tid] = v + a;
        __syncthreads();
    }
    uint run = (tid > 0) ? tsum[tid - 1] : 0u;
    for (int i = beg; i < end; i++) { rowptr[i] = (int)run; run += deg[i]; }
    if (tid == 255) rowptr[N0] = (int)run;
}

__global__ void k_scatter(const int* src, const int* dst, const int* rowptr,
                          uint* cnt, int* csr) {
    int e = blockIdx.x * blockDim.x + threadIdx.x;
    if (e < NE) {
        int d = dst[e];
        uint p = atomicAdd(&cnt[d], 1u);
        csr[rowptr[d] + (int)p] = src[e];
    }
}

// ---------- conv1 (graph 0) ----------
__global__ void k_xw1(const float* x, const float* W1, float* xw1) {
    int t = blockIdx.x * blockDim.x + threadIdx.x;
    if (t >= N0 * H1C) return;
    int i = t >> 6, h = t & 63;
    float acc = 0.f;
#pragma unroll
    for (int f = 0; f < FIN; f++) acc += x[i * FIN + f] * W1[f * H1C + h];
    xw1[t] = acc;
}

__global__ void k_dinv(const uint* deg, float* dinv) {
    int i = blockIdx.x * blockDim.x + threadIdx.x;
    if (i < N0) dinv[i] = rsqrtf(1.0f + (float)deg[i]);
}

// gather conv1 messages + finish h1 (fused fin1), 4-way unrolled
__global__ void k_gath1(const int* rowptr, const int* csr, const float* dinv,
                        const float* xw1, const float* b1, float* h1) {
    int wid = (blockIdx.x * blockDim.x + threadIdx.x) >> 6;
    int lane = threadIdx.x & 63;
    if (wid >= N0) return;
    int d = wid;
    int beg = rowptr[d], end = rowptr[d + 1];
    float a0 = 0.f, a1 = 0.f, a2 = 0.f, a3 = 0.f;
    int e = beg;
    for (; e + 4 <= end; e += 4) {
        int s0 = csr[e], s1 = csr[e + 1], s2 = csr[e + 2], s3 = csr[e + 3];
        a0 += xw1[(size_t)s0 * H1C + lane] * dinv[s0];
        a1 += xw1[(size_t)s1 * H1C + lane] * dinv[s1];
        a2 += xw1[(size_t)s2 * H1C + lane] * dinv[s2];
        a3 += xw1[(size_t)s3 * H1C + lane] * dinv[s3];
    }
    for (; e < end; e++) {
        int s = csr[e];
        a0 += xw1[(size_t)s * H1C + lane] * dinv[s];
    }
    float acc = (a0 + a1) + (a2 + a3);
    float did = dinv[d];
    float v = acc * did + xw1[(size_t)d * H1C + lane] * did * did + b1[lane];
    h1[(size_t)d * H1C + lane] = fmaxf(v, 0.f);
}

// ---------- pooling score ----------
__global__ void k_h1w(const float* h1, const float* Wp, float* h1w) {
    int i = blockIdx.x * blockDim.x + threadIdx.x;
    if (i >= N0) return;
    const float* row = h1 + (size_t)i * H1C;
    float acc = 0.f;
#pragma unroll
    for (int h = 0; h < H1C; h++) acc += row[h] * Wp[h];
    h1w[i] = acc;
}

// graph-0 score: gather + self-loop (fused smsg+score0)
__global__ void k_gscore0(const int* rowptr, const int* csr, const float* dinv,
                          const float* h1w, const float* bp, float* score) {
    int d = blockIdx.x * blockDim.x + threadIdx.x;
    if (d >= N0) return;
    float acc = 0.f;
    int beg = rowptr[d], end = rowptr[d + 1];
    for (int e = beg; e < end; e++) {
        int s = csr[e];
        acc += h1w[s] * dinv[s];
    }
    float did = dinv[d];
    score[d] = acc * did + h1w[d] * did * did + bp[0];
}

// graphs 1..63: score = relu(x@W1+b1) . Wp + bp
// Weights staged in LDS: sW[h*8] = {W1[0..5][h], b1[h], Wp[h]}.
__global__ void k_score_rest(const float* __restrict__ x, const float* __restrict__ W1,
                             const float* __restrict__ b1, const float* __restrict__ Wp,
                             const float* __restrict__ bp, float* score) {
    __shared__ __align__(16) float sW[H1C * 8];
    int tid = threadIdx.x;
    if (tid < H1C) {
#pragma unroll
        for (int f = 0; f < FIN; f++) sW[tid * 8 + f] = W1[f * H1C + tid];
        sW[tid * 8 + 6] = b1[tid];
        sW[tid * 8 + 7] = Wp[tid];
    }
    __syncthreads();
    int idx = blockIdx.x * blockDim.x + tid;
    int n = N0 + idx;
    if (n >= NT) return;
    const float2* xv = reinterpret_cast<const float2*>(x) + (size_t)n * 3;
    float2 x01 = xv[0], x23 = xv[1], x45 = xv[2];
    float sc = bp[0];
#pragma unroll
    for (int h = 0; h < H1C; h++) {
        float4 wa = *reinterpret_cast<const float4*>(&sW[h * 8]);
        float4 wb = *reinterpret_cast<const float4*>(&sW[h * 8 + 4]);
        float a = wb.z;                       // b1[h]
        a += x01.x * wa.x; a += x01.y * wa.y;
        a += x23.x * wa.z; a += x23.y * wa.w;
        a += x45.x * wb.x; a += x45.y * wb.y;
        sc += fmaxf(a, 0.f) * wb.w;           // Wp[h]
    }
    score[n] = sc;
}

// ---------- per-graph top-K selection (radix select on float keys) ----------
__global__ void k_topk(const float* score, uchar* sel) {
    int g = blockIdx.x;
    const float* sc = score + (size_t)g * N0;
    uchar* sl = sel + (size_t)g * N0;
    __shared__ uint hist[4][256];
    __shared__ uint shPrefix, shWant;
    __shared__ uint wtot[4];
    int tid = threadIdx.x;
    int wave = tid >> 6, lane = tid & 63;
    uint prefix = 0, want = KSEL;
    for (int pass = 0; pass < 4; pass++) {
        int shift = 24 - 8 * pass;
#pragma unroll
        for (int w = 0; w < 4; w++) hist[w][tid] = 0;
        __syncthreads();
        for (int i = tid; i < N0; i += 256) {
            uint k = keyOf(sc[i]);
            bool active = (pass == 0) || ((k >> (shift + 8)) == prefix);
            if (active) atomicAdd(&hist[wave][(k >> shift) & 255], 1u);
        }
        __syncthreads();
        uint merged = hist[0][tid] + hist[1][tid] + hist[2][tid] + hist[3][tid];
        hist[0][tid] = merged;
        __syncthreads();
        if (tid == 0) {
            uint cum = 0; int d = 255;
            for (; d > 0; d--) { cum += hist[0][d]; if (cum >= want) break; }
            if (cum < want) cum += hist[0][0];        // d==0 fallthrough
            shWant = want - (cum - hist[0][d]);
            shPrefix = (prefix << 8) | (uint)d;
        }
        __syncthreads();
        prefix = shPrefix; want = shWant;
        __syncthreads();
    }
    uint T = prefix, needEq = want;
    uint runningEq = 0;
    for (int base = 0; base < N0; base += 256) {
        int i = base + tid;
        uint k = (i < N0) ? keyOf(sc[i]) : 0u;
        bool isEq = (i < N0) && (k == T);
        unsigned long long mask = __ballot(isEq);
        uint wprefix = (uint)__popcll(mask & ((1ull << lane) - 1ull));
        uint wcount = (uint)__popcll(mask);
        if (lane == 0) wtot[wave] = wcount;
        __syncthreads();
        uint before = 0;
#pragma unroll
        for (int w = 0; w < 4; w++) if (w < wave) before += wtot[w];
        uint total = wtot[0] + wtot[1] + wtot[2] + wtot[3];
        if (i < N0) {
            uchar s = 0;
            if (k > T) s = 1;
            else if (isEq && (runningEq + before + wprefix) < needEq) s = 1;
            sl[i] = s;
        }
        runningEq += total;
        __syncthreads();
    }
}

// ---------- conv2 (graph 0, selection-filtered) ----------
__global__ void k_gdinv2(const int* rowptr, const int* csr, const uchar* sel,
                         float* dinv2) {
    int d = blockIdx.x * blockDim.x + threadIdx.x;
    if (d >= N0) return;
    float r = 0.f;
    if (sel[d]) {
        int c = 0;
        int beg = rowptr[d], end = rowptr[d + 1];
        for (int e = beg; e < end; e++) c += sel[csr[e]];
        r = rsqrtf(1.f + (float)c);
    }
    dinv2[d] = r;
}

__global__ void k_xw2(const float* h1, const float* score, const uchar* sel,
                      const float* W2, float* xw2) {
    int gt = blockIdx.x * blockDim.x + threadIdx.x;
    int i = gt >> 5, c = gt & 31;
    if (i >= N0) return;
    if (!sel[i]) return;
    float t = tanhf(score[i]);
    const float* row = h1 + (size_t)i * H1C;
    float acc = 0.f;
#pragma unroll
    for (int h = 0; h < H1C; h++) acc += row[h] * W2[h * H2C + c];
    xw2[i * H2C + c] = acc * t;
}

__global__ void k_gath2(const int* rowptr, const int* csr, const uchar* sel,
                        const float* dinv2, const float* xw2, float* acc2) {
    int wid = (blockIdx.x * blockDim.x + threadIdx.x) >> 6;
    int lane = threadIdx.x & 63;
    if (wid >= N0) return;
    int d = wid;
    if (!sel[d]) return;
    int c = lane & 31;
    int beg = rowptr[d], end = rowptr[d + 1];
    float a0 = 0.f, a1 = 0.f;
    int e = beg + (lane >> 5);
    for (; e + 2 < end; e += 4) {   // this half-wave handles e, e+2
        int s0 = csr[e], s1 = csr[e + 2];
        a0 += xw2[(size_t)s0 * H2C + c] * dinv2[s0];
        a1 += xw2[(size_t)s1 * H2C + c] * dinv2[s1];
    }
    if (e < end) {
        int s = csr[e];
        a0 += xw2[(size_t)s * H2C + c] * dinv2[s];
    }
    float acc = a0 + a1;
    acc += __shfl_xor(acc, 32, 64);
    if (lane < 32) acc2[(size_t)d * H2C + c] = acc * dinv2[d];
}

__global__ void k_fin2(const float* acc2, const float* xw2, const float* dinv2,
                       const uchar* sel, const float* b2, float* gmax) {
    __shared__ float m[32];
    int tid = threadIdx.x;
    if (tid < 32) m[tid] = 0.f;
    __syncthreads();
    int i = blockIdx.x * 8 + (tid >> 5);
    int c = tid & 31;
    float v = 0.f;
    if (i < N0 && sel[i]) {
        float di = dinv2[i];
        v = fmaxf(acc2[(size_t)i * H2C + c] + xw2[(size_t)i * H2C + c] * di * di + b2[c], 0.f);
    }
    atomicMax((int*)&m[c], __float_as_int(v));
    __syncthreads();
    if (tid < 32) atomicMax((int*)&gmax[tid], __float_as_int(m[tid]));
}

// ---------- graphs 1..63: h2 + max pool via MFMA bf16 ----------
// Per wave: 64 nodes in 4 groups of 16. Layer1 (hv) in fp32 from LDS-staged
// W1 (tanh folded into hv), layer2 via mfma_f32_16x16x32_bf16:
//   A[node=lane&15][k=(lane>>4)*8+j] = bf16(t*relu(W1^T x + b1)) (2 k-halves)
//   B[k][c=lane&15] = bf16(W2), 4 frags held in VGPR (2 khalf x 2 ctile)
//   D: col=lane&15 (channel), row=(lane>>4)*4+reg (node)  [guide m89]
// Masked relu+max epilogue; per-wave LDS atomic merge, per-block global.
#define BPGR 68
__global__ __launch_bounds__(256, 4)
void k_rest_pool(const float* __restrict__ x, const float* __restrict__ score,
                 const uchar* __restrict__ sel,
                 const float* __restrict__ W1, const float* __restrict__ b1,
                 const float* __restrict__ W2, const float* __restrict__ b2,
                 float* gmax) {
    __shared__ __align__(16) float sW1[H1C * 8];
    __shared__ float m[H2C];
    int tid = threadIdx.x;
    if (tid < H2C) m[tid] = 0.f;
    if (tid < H1C) {
#pragma unroll
        for (int f = 0; f < FIN; f++) sW1[tid * 8 + f] = W1[f * H1C + tid];
        sW1[tid * 8 + 6] = b1[tid];
        sW1[tid * 8 + 7] = 0.f;
    }
    __syncthreads();

    int lane = tid & 63;
    int g = blockIdx.x / BPGR + 1;
    int wslot = (blockIdx.x % BPGR) * 4 + (tid >> 6);
    int nbase = wslot * 64;
    int col = lane & 15;
    int kbase = (lane >> 4) * 8;

    // B fragments (held in VGPR, reused by all 4 groups)
    bf16x8 B00, B10, B01, B11;
#pragma unroll
    for (int j = 0; j < 8; j++) {
        int k = kbase + j;
        B00[j] = f2bf(W2[k * H2C + col]);
        B10[j] = f2bf(W2[(32 + k) * H2C + col]);
        B01[j] = f2bf(W2[k * H2C + col + 16]);
        B11[j] = f2bf(W2[(32 + k) * H2C + col + 16]);
    }
    float b2c0 = b2[col], b2c1 = b2[col + 16];

    // hoisted per-node tanh/mask for this wave's 64 nodes (node = nbase+lane)
    {
        // computed below into tl_all/mk_all
    }
    int liw = nbase + lane;
    bool inbw = liw < N0;
    int nw = g * N0 + (inbw ? liw : 0);
    bool validw = inbw && sel[nw];
    float tl_all = validw ? tanhf(score[nw]) : 0.f;
    float mk_all = validw ? 1.f : 0.f;

    float rm0 = 0.f, rm1 = 0.f;
#pragma unroll 1
    for (int grp = 0; grp < 4; grp++) {
        int li = nbase + grp * 16 + col;
        int n = g * N0 + ((li < N0) ? li : 0);
        float tlA = __shfl(tl_all, grp * 16 + col, 64);
        float2 x01 = {0.f, 0.f}, x23 = {0.f, 0.f}, x45 = {0.f, 0.f};
        if (tlA != 0.f) {
            const float2* xv = reinterpret_cast<const float2*>(x) + (size_t)n * 3;
            x01 = xv[0]; x23 = xv[1]; x45 = xv[2];
        }
        bf16x8 A0, A1;
#pragma unroll
        for (int j = 0; j < 8; j++) {
            const float* r0 = &sW1[(kbase + j) * 8];
            float4 wa = *reinterpret_cast<const float4*>(r0);
            float4 wb = *reinterpret_cast<const float4*>(r0 + 4);
            float a = wb.z;
            a += x01.x * wa.x; a += x01.y * wa.y;
            a += x23.x * wa.z; a += x23.y * wa.w;
            a += x45.x * wb.x; a += x45.y * wb.y;
            A0[j] = f2bf(tlA * fmaxf(a, 0.f));
            const float* r1 = &sW1[(32 + kbase + j) * 8];
            float4 va = *reinterpret_cast<const float4*>(r1);
            float4 vb = *reinterpret_cast<const float4*>(r1 + 4);
            float b = vb.z;
            b += x01.x * va.x; b += x01.y * va.y;
            b += x23.x * va.z; b += x23.y * va.w;
            b += x45.x * vb.x; b += x45.y * vb.y;
            A1[j] = f2bf(tlA * fmaxf(b, 0.f));
        }
        f32x4 acc0 = {0.f, 0.f, 0.f, 0.f};
        f32x4 acc1 = {0.f, 0.f, 0.f, 0.f};
        acc0 = __builtin_amdgcn_mfma_f32_16x16x32_bf16(A0, B00, acc0, 0, 0, 0);
        acc0 = __builtin_amdgcn_mfma_f32_16x16x32_bf16(A1, B10, acc0, 0, 0, 0);
        acc1 = __builtin_amdgcn_mfma_f32_16x16x32_bf16(A0, B01, acc1, 0, 0, 0);
        acc1 = __builtin_amdgcn_mfma_f32_16x16x32_bf16(A1, B11, acc1, 0, 0, 0);
#pragma unroll
        for (int reg = 0; reg < 4; reg++) {
            int srcnode = (lane >> 4) * 4 + reg;         // D row = node in group
            float mr = __shfl(mk_all, grp * 16 + srcnode, 64);
            float v0 = mr * fmaxf(acc0[reg] + b2c0, 0.f);
            float v1 = mr * fmaxf(acc1[reg] + b2c1, 0.f);
            rm0 = fmaxf(rm0, v0);
            rm1 = fmaxf(rm1, v1);
        }
    }
    rm0 = fmaxf(rm0, __shfl_xor(rm0, 16, 64));
    rm0 = fmaxf(rm0, __shfl_xor(rm0, 32, 64));
    rm1 = fmaxf(rm1, __shfl_xor(rm1, 16, 64));
    rm1 = fmaxf(rm1, __shfl_xor(rm1, 32, 64));
    if (lane < 16) {
        atomicMax((int*)&m[col], __float_as_int(rm0));
        atomicMax((int*)&m[col + 16], __float_as_int(rm1));
    }
    __syncthreads();
    if (tid < H2C) atomicMax((int*)&gmax[g * H2C + tid], __float_as_int(m[tid]));
}

// ---------- readout ----------
__global__ void k_final(const float* gmax, const float* Wf, const float* bf, float* out) {
    int g = threadIdx.x;
    if (g < BATCH) {
        float acc = bf[0];
        for (int c = 0; c < H2C; c++) acc += gmax[g * H2C + c] * Wf[c];
        out[g] = 1.f / (1.f + expf(-acc));
    }
}

extern "C" void kernel_launch(void* const* d_in, const int* in_sizes, int n_in,
                              void* d_out, int out_size, void* d_ws, size_t ws_size,
                              hipStream_t stream) {
    const float* data = (const float*)d_in[0];
    const void*  ei   = d_in[1];
    const float* W1   = (const float*)d_in[2];
    const float* b1   = (const float*)d_in[3];
    const float* Wp   = (const float*)d_in[4];
    const float* bp   = (const float*)d_in[5];
    const float* W2   = (const float*)d_in[6];
    const float* b2   = (const float*)d_in[7];
    const float* Wf   = (const float*)d_in[8];
    const float* bf   = (const float*)d_in[9];
    float* out = (float*)d_out;

    char* ws = (char*)d_ws;
    size_t off = 0;
    auto A = [&](size_t bytes) -> size_t {
        size_t o = off; off += (bytes + 511) & ~(size_t)511; return o;
    };
    // zero-initialized region (single memset)
    size_t o_deg0 = A((size_t)N0 * 4);
    size_t o_cnt  = A((size_t)N0 * 4);
    size_t o_gmax = A((size_t)BATCH * H2C * 4);
    size_t zbytes = off;
    // rest
    size_t o_src  = A((size_t)NE * 4);
    size_t o_dst  = A((size_t)NE * 4);
    size_t o_rp   = A((size_t)(N0 + 1) * 4);
    size_t o_csr  = A((size_t)NE * 4);
    size_t o_xw1  = A((size_t)N0 * H1C * 4);
    size_t o_h1   = A((size_t)N0 * H1C * 4);
    size_t o_di0  = A((size_t)N0 * 4);
    size_t o_di2  = A((size_t)N0 * 4);
    size_t o_h1w  = A((size_t)N0 * 4);
    size_t o_scr  = A((size_t)NT * 4);
    size_t o_sel  = A((size_t)NT);
    size_t o_xw2  = A((size_t)N0 * H2C * 4);
    size_t o_acc2 = A((size_t)N0 * H2C * 4);
    size_t o_flag = A(4);

    uint*  deg0 = (uint*)(ws + o_deg0);
    uint*  cnt  = (uint*)(ws + o_cnt);
    float* gmax = (float*)(ws + o_gmax);
    int*   src  = (int*)(ws + o_src);
    int*   dst  = (int*)(ws + o_dst);
    int*   rp   = (int*)(ws + o_rp);
    int*   csr  = (int*)(ws + o_csr);
    float* xw1  = (float*)(ws + o_xw1);
    float* h1   = (float*)(ws + o_h1);
    float* di0  = (float*)(ws + o_di0);
    float* di2  = (float*)(ws + o_di2);
    float* h1w  = (float*)(ws + o_h1w);
    float* scr  = (float*)(ws + o_scr);
    uchar* sel  = (uchar*)(ws + o_sel);
    float* xw2  = (float*)(ws + o_xw2);
    float* acc2 = (float*)(ws + o_acc2);
    int*   flag = (int*)(ws + o_flag);

    hipMemsetAsync(ws, 0, zbytes, stream);

    k_detect<<<1, 256, 0, stream>>>((const uint*)ei, flag);
    k_convert<<<2048, 256, 0, stream>>>(ei, flag, src, dst);
    k_deg<<<(NE + 255) / 256, 256, 0, stream>>>(dst, deg0);
    k_scan<<<1, 256, 0, stream>>>(deg0, rp);
    k_scatter<<<(NE + 255) / 256, 256, 0, stream>>>(src, dst, rp, cnt, csr);
    k_xw1<<<(N0 * H1C + 255) / 256, 256, 0, stream>>>(data, W1, xw1);
    k_dinv<<<(N0 + 255) / 256, 256, 0, stream>>>(deg0, di0);
    k_gath1<<<(N0 * 64 + 255) / 256, 256, 0, stream>>>(rp, csr, di0, xw1, b1, h1);
    k_h1w<<<(N0 + 255) / 256, 256, 0, stream>>>(h1, Wp, h1w);
    k_gscore0<<<(N0 + 255) / 256, 256, 0, stream>>>(rp, csr, di0, h1w, bp, scr);
    k_score_rest<<<(NT - N0 + 255) / 256, 256, 0, stream>>>(data, W1, b1, Wp, bp, scr);
    k_topk<<<BATCH, 256, 0, stream>>>(scr, sel);
    k_gdinv2<<<(N0 + 255) / 256, 256, 0, stream>>>(rp, csr, sel, di2);
    k_xw2<<<(N0 * H2C + 255) / 256, 256, 0, stream>>>(h1, scr, sel, W2, xw2);
    k_gath2<<<(N0 * 64 + 255) / 256, 256, 0, stream>>>(rp, csr, sel, di2, xw2, acc2);
    k_fin2<<<(N0 + 7) / 8, 256, 0, stream>>>(acc2, xw2, di2, sel, b2, gmax);
    k_rest_pool<<<(BATCH - 1) * BPGR, 256, 0, stream>>>(data, scr, sel, W1, b1, W2, b2, gmax);
    k_final<<<1, 64, 0, stream>>>(gmax, Wf, bf, out);
}

// Round 9
// 528.004 us; speedup vs baseline: 11.7776x; 1.0362x over previous
//
#include <hip/hip_runtime.h>
#include <hip/hip_bf16.h>
#include <math.h>

#define N0   17186
#define FIN  6
#define H1C  64
#define H2C  32
#define KSEL 12031
#define BATCH 64
#define NE   500000
#define NT   (BATCH * N0)

typedef unsigned int uint;
typedef unsigned char uchar;
typedef __attribute__((ext_vector_type(8))) short bf16x8;
typedef __attribute__((ext_vector_type(4))) float f32x4;

__device__ __forceinline__ uint keyOf(float f) {
    uint u = __float_as_uint(f);
    return (u & 0x80000000u) ? ~u : (u | 0x80000000u);
}

__device__ __forceinline__ short f2bf(float f) {
    union { __hip_bfloat16 b; short s; } u;
    u.b = __float2bfloat16(f);
    return u.s;
}

// ---------- edge dtype detection / normalization ----------
__global__ void k_detect(const uint* ei, int* flag64) {
    __shared__ int any;
    if (threadIdx.x == 0) any = 0;
    __syncthreads();
    for (int i = threadIdx.x; i < 1024; i += blockDim.x)
        if (ei[2 * i + 1] != 0u) any = 1;
    __syncthreads();
    if (threadIdx.x == 0) *flag64 = any ? 0 : 1;
}

__global__ void k_convert(const void* ei, const int* flag64, int* src, int* dst) {
    int f = *flag64;
    int stride = gridDim.x * blockDim.x;
    for (int i = blockIdx.x * blockDim.x + threadIdx.x; i < 2 * NE; i += stride) {
        int v = f ? (int)((const long long*)ei)[i] : ((const int*)ei)[i];
        if (i < NE) src[i] = v; else dst[i - NE] = v;
    }
}

// ---------- CSR build ----------
__global__ void k_deg(const int* dst, uint* deg) {
    int e = blockIdx.x * blockDim.x + threadIdx.x;
    if (e < NE) atomicAdd(&deg[dst[e]], 1u);
}

__global__ void k_scan(const uint* deg, int* rowptr) {
    __shared__ uint tsum[256];
    int tid = threadIdx.x;
    const int CH = (N0 + 255) / 256;  // 68
    int beg = tid * CH, end = beg + CH;
    if (end > N0) end = N0;
    uint s = 0;
    for (int i = beg; i < end; i++) s += deg[i];
    tsum[tid] = s;
    __syncthreads();
    for (int off = 1; off < 256; off <<= 1) {
        uint v = tsum[tid];
        uint a = (tid >= off) ? tsum[tid - off] : 0u;
        __syncthreads();
        tsum[tid] = v + a;
        __syncthreads();
    }
    uint run = (tid > 0) ? tsum[tid - 1] : 0u;
    for (int i = beg; i < end; i++) { rowptr[i] = (int)run; run += deg[i]; }
    if (tid == 255) rowptr[N0] = (int)run;
}

__global__ void k_scatter(const int* src, const int* dst, const int* rowptr,
                          uint* cnt, int* csr) {
    int e = blockIdx.x * blockDim.x + threadIdx.x;
    if (e < NE) {
        int d = dst[e];
        uint p = atomicAdd(&cnt[d], 1u);
        csr[rowptr[d] + (int)p] = src[e];
    }
}

// ---------- conv1 (graph 0) ----------
__global__ void k_xw1(const float* x, const float* W1, float* xw1) {
    int t = blockIdx.x * blockDim.x + threadIdx.x;
    if (t >= N0 * H1C) return;
    int i = t >> 6, h = t & 63;
    float acc = 0.f;
#pragma unroll
    for (int f = 0; f < FIN; f++) acc += x[i * FIN + f] * W1[f * H1C + h];
    xw1[t] = acc;
}

__global__ void k_dinv(const uint* deg, float* dinv) {
    int i = blockIdx.x * blockDim.x + threadIdx.x;
    if (i < N0) dinv[i] = rsqrtf(1.0f + (float)deg[i]);
}

// gather conv1 messages + finish h1 (fused fin1), 4-way unrolled
__global__ void k_gath1(const int* rowptr, const int* csr, const float* dinv,
                        const float* xw1, const float* b1, float* h1) {
    int wid = (blockIdx.x * blockDim.x + threadIdx.x) >> 6;
    int lane = threadIdx.x & 63;
    if (wid >= N0) return;
    int d = wid;
    int beg = rowptr[d], end = rowptr[d + 1];
    float a0 = 0.f, a1 = 0.f, a2 = 0.f, a3 = 0.f;
    int e = beg;
    for (; e + 4 <= end; e += 4) {
        int s0 = csr[e], s1 = csr[e + 1], s2 = csr[e + 2], s3 = csr[e + 3];
        a0 += xw1[(size_t)s0 * H1C + lane] * dinv[s0];
        a1 += xw1[(size_t)s1 * H1C + lane] * dinv[s1];
        a2 += xw1[(size_t)s2 * H1C + lane] * dinv[s2];
        a3 += xw1[(size_t)s3 * H1C + lane] * dinv[s3];
    }
    for (; e < end; e++) {
        int s = csr[e];
        a0 += xw1[(size_t)s * H1C + lane] * dinv[s];
    }
    float acc = (a0 + a1) + (a2 + a3);
    float did = dinv[d];
    float v = acc * did + xw1[(size_t)d * H1C + lane] * did * did + b1[lane];
    h1[(size_t)d * H1C + lane] = fmaxf(v, 0.f);
}

// ---------- pooling score ----------
__global__ void k_h1w(const float* h1, const float* Wp, float* h1w) {
    int i = blockIdx.x * blockDim.x + threadIdx.x;
    if (i >= N0) return;
    const float* row = h1 + (size_t)i * H1C;
    float acc = 0.f;
#pragma unroll
    for (int h = 0; h < H1C; h++) acc += row[h] * Wp[h];
    h1w[i] = acc;
}

// graph-0 score: gather + self-loop (fused smsg+score0)
__global__ void k_gscore0(const int* rowptr, const int* csr, const float* dinv,
                          const float* h1w, const float* bp, float* score) {
    int d = blockIdx.x * blockDim.x + threadIdx.x;
    if (d >= N0) return;
    float acc = 0.f;
    int beg = rowptr[d], end = rowptr[d + 1];
    for (int e = beg; e < end; e++) {
        int s = csr[e];
        acc += h1w[s] * dinv[s];
    }
    float did = dinv[d];
    score[d] = acc * did + h1w[d] * did * did + bp[0];
}

// graphs 1..63: score = relu(x@W1+b1) . Wp + bp
// Weights staged in LDS: sW[h*8] = {W1[0..5][h], b1[h], Wp[h]} (broadcast reads).
__global__ void k_score_rest(const float* __restrict__ x, const float* __restrict__ W1,
                             const float* __restrict__ b1, const float* __restrict__ Wp,
                             const float* __restrict__ bp, float* score) {
    __shared__ __align__(16) float sW[H1C * 8];
    int tid = threadIdx.x;
    if (tid < H1C) {
#pragma unroll
        for (int f = 0; f < FIN; f++) sW[tid * 8 + f] = W1[f * H1C + tid];
        sW[tid * 8 + 6] = b1[tid];
        sW[tid * 8 + 7] = Wp[tid];
    }
    __syncthreads();
    int idx = blockIdx.x * blockDim.x + tid;
    int n = N0 + idx;
    if (n >= NT) return;
    const float2* xv = reinterpret_cast<const float2*>(x) + (size_t)n * 3;
    float2 x01 = xv[0], x23 = xv[1], x45 = xv[2];
    float sc = bp[0];
#pragma unroll
    for (int h = 0; h < H1C; h++) {
        float4 wa = *reinterpret_cast<const float4*>(&sW[h * 8]);
        float4 wb = *reinterpret_cast<const float4*>(&sW[h * 8 + 4]);
        float a = wb.z;                       // b1[h]
        a += x01.x * wa.x; a += x01.y * wa.y;
        a += x23.x * wa.z; a += x23.y * wa.w;
        a += x45.x * wb.x; a += x45.y * wb.y;
        sc += fmaxf(a, 0.f) * wb.w;           // Wp[h]
    }
    score[n] = sc;
}

// ---------- per-graph top-K selection (radix select on float keys) ----------
__global__ void k_topk(const float* score, uchar* sel) {
    int g = blockIdx.x;
    const float* sc = score + (size_t)g * N0;
    uchar* sl = sel + (size_t)g * N0;
    __shared__ uint hist[4][256];
    __shared__ uint shPrefix, shWant;
    __shared__ uint wtot[4];
    int tid = threadIdx.x;
    int wave = tid >> 6, lane = tid & 63;
    uint prefix = 0, want = KSEL;
    for (int pass = 0; pass < 4; pass++) {
        int shift = 24 - 8 * pass;
#pragma unroll
        for (int w = 0; w < 4; w++) hist[w][tid] = 0;
        __syncthreads();
        for (int i = tid; i < N0; i += 256) {
            uint k = keyOf(sc[i]);
            bool active = (pass == 0) || ((k >> (shift + 8)) == prefix);
            if (active) atomicAdd(&hist[wave][(k >> shift) & 255], 1u);
        }
        __syncthreads();
        uint merged = hist[0][tid] + hist[1][tid] + hist[2][tid] + hist[3][tid];
        hist[0][tid] = merged;
        __syncthreads();
        if (tid == 0) {
            uint cum = 0; int d = 255;
            for (; d > 0; d--) { cum += hist[0][d]; if (cum >= want) break; }
            if (cum < want) cum += hist[0][0];        // d==0 fallthrough
            shWant = want - (cum - hist[0][d]);
            shPrefix = (prefix << 8) | (uint)d;
        }
        __syncthreads();
        prefix = shPrefix; want = shWant;
        __syncthreads();
    }
    uint T = prefix, needEq = want;
    uint runningEq = 0;
    for (int base = 0; base < N0; base += 256) {
        int i = base + tid;
        uint k = (i < N0) ? keyOf(sc[i]) : 0u;
        bool isEq = (i < N0) && (k == T);
        unsigned long long mask = __ballot(isEq);
        uint wprefix = (uint)__popcll(mask & ((1ull << lane) - 1ull));
        uint wcount = (uint)__popcll(mask);
        if (lane == 0) wtot[wave] = wcount;
        __syncthreads();
        uint before = 0;
#pragma unroll
        for (int w = 0; w < 4; w++) if (w < wave) before += wtot[w];
        uint total = wtot[0] + wtot[1] + wtot[2] + wtot[3];
        if (i < N0) {
            uchar s = 0;
            if (k > T) s = 1;
            else if (isEq && (runningEq + before + wprefix) < needEq) s = 1;
            sl[i] = s;
        }
        runningEq += total;
        __syncthreads();
    }
}

// ---------- conv2 (graph 0, selection-filtered) ----------
__global__ void k_gdinv2(const int* rowptr, const int* csr, const uchar* sel,
                         float* dinv2) {
    int d = blockIdx.x * blockDim.x + threadIdx.x;
    if (d >= N0) return;
    float r = 0.f;
    if (sel[d]) {
        int c = 0;
        int beg = rowptr[d], end = rowptr[d + 1];
        for (int e = beg; e < end; e++) c += sel[csr[e]];
        r = rsqrtf(1.f + (float)c);
    }
    dinv2[d] = r;
}

__global__ void k_xw2(const float* h1, const float* score, const uchar* sel,
                      const float* W2, float* xw2) {
    int gt = blockIdx.x * blockDim.x + threadIdx.x;
    int i = gt >> 5, c = gt & 31;
    if (i >= N0) return;
    if (!sel[i]) return;
    float t = tanhf(score[i]);
    const float* row = h1 + (size_t)i * H1C;
    float acc = 0.f;
#pragma unroll
    for (int h = 0; h < H1C; h++) acc += row[h] * W2[h * H2C + c];
    xw2[i * H2C + c] = acc * t;
}

__global__ void k_gath2(const int* rowptr, const int* csr, const uchar* sel,
                        const float* dinv2, const float* xw2, float* acc2) {
    int wid = (blockIdx.x * blockDim.x + threadIdx.x) >> 6;
    int lane = threadIdx.x & 63;
    if (wid >= N0) return;
    int d = wid;
    if (!sel[d]) return;
    int c = lane & 31;
    int beg = rowptr[d], end = rowptr[d + 1];
    float a0 = 0.f, a1 = 0.f;
    int e = beg + (lane >> 5);
    for (; e + 2 < end; e += 4) {   // this half-wave handles e, e+2
        int s0 = csr[e], s1 = csr[e + 2];
        a0 += xw2[(size_t)s0 * H2C + c] * dinv2[s0];
        a1 += xw2[(size_t)s1 * H2C + c] * dinv2[s1];
    }
    if (e < end) {
        int s = csr[e];
        a0 += xw2[(size_t)s * H2C + c] * dinv2[s];
    }
    float acc = a0 + a1;
    acc += __shfl_xor(acc, 32, 64);
    if (lane < 32) acc2[(size_t)d * H2C + c] = acc * dinv2[d];
}

__global__ void k_fin2(const float* acc2, const float* xw2, const float* dinv2,
                       const uchar* sel, const float* b2, float* gmax) {
    __shared__ float m[32];
    int tid = threadIdx.x;
    if (tid < 32) m[tid] = 0.f;
    __syncthreads();
    int i = blockIdx.x * 8 + (tid >> 5);
    int c = tid & 31;
    float v = 0.f;
    if (i < N0 && sel[i]) {
        float di = dinv2[i];
        v = fmaxf(acc2[(size_t)i * H2C + c] + xw2[(size_t)i * H2C + c] * di * di + b2[c], 0.f);
    }
    atomicMax((int*)&m[c], __float_as_int(v));
    __syncthreads();
    if (tid < 32) atomicMax((int*)&gmax[tid], __float_as_int(m[tid]));
}

// ---------- graphs 1..63: h2 + max pool via MFMA bf16 (v3) ----------
// R8 pathologies fixed:
//  - no persistent B-frags: bf16 W2^T staged in LDS [32][72] shorts (144B row
//    stride -> quarter-waves on distinct banks, <=2-way = free), frag loaded
//    via one ds_read_b128 right before each MFMA. Peak live ~45 VGPR, no spill.
//  - sW1 XOR-swizzle (dword ^= ((h>>3)&1)<<2): 4-way bank conflict -> 2-way.
//  - tanh/mask via LDS arrays ltl/lmk (conflict-free broadcast), no dynamic shfl.
#define BPGR 68
__global__ __launch_bounds__(256, 4)
void k_rest_pool(const float* __restrict__ x, const float* __restrict__ score,
                 const uchar* __restrict__ sel,
                 const float* __restrict__ W1, const float* __restrict__ b1,
                 const float* __restrict__ W2, const float* __restrict__ b2,
                 float* gmax) {
    __shared__ __align__(16) float sW1[H1C * 8];
    __shared__ __align__(16) short sW2T[H2C * 72];
    __shared__ float ltl[256];
    __shared__ float lmk[256];
    __shared__ float m[H2C];
    int tid = threadIdx.x;
    if (tid < H2C) m[tid] = 0.f;
    if (tid < H1C) {
        int h = tid;
        int swz = ((h >> 3) & 1) << 2;
        int blo = (h * 8) ^ swz;
        int bhi = (h * 8 + 4) ^ swz;
        sW1[blo + 0] = W1[0 * H1C + h];
        sW1[blo + 1] = W1[1 * H1C + h];
        sW1[blo + 2] = W1[2 * H1C + h];
        sW1[blo + 3] = W1[3 * H1C + h];
        sW1[bhi + 0] = W1[4 * H1C + h];
        sW1[bhi + 1] = W1[5 * H1C + h];
        sW1[bhi + 2] = b1[h];
        sW1[bhi + 3] = 0.f;
    }
    {   // W2^T bf16 staging: sW2T[c][k], row stride 72 shorts
        int c = tid >> 3, k0 = (tid & 7) * 8;
#pragma unroll
        for (int k = 0; k < 8; k++)
            sW2T[c * 72 + k0 + k] = f2bf(W2[(k0 + k) * H2C + c]);
    }
    int lane = tid & 63;
    int wv = tid >> 6;
    int g = blockIdx.x / BPGR + 1;
    int wslot = (blockIdx.x % BPGR) * 4 + wv;
    int nbase = wslot * 64;
    {   // per-node tanh / mask for this wave's 64 nodes
        int li = nbase + lane;
        bool inb = li < N0;
        int n = g * N0 + (inb ? li : 0);
        bool valid = inb && sel[n];
        ltl[tid] = valid ? tanhf(score[n]) : 0.f;
        lmk[tid] = valid ? 1.f : 0.f;
    }
    __syncthreads();

    int col = lane & 15;
    int q = lane >> 4;
    int kb8 = q * 8;
    int wbase = wv * 64;
    float b2c0 = b2[col], b2c1 = b2[col + 16];
    float rm0 = 0.f, rm1 = 0.f;
#pragma unroll 1
    for (int grp = 0; grp < 4; grp++) {
        float tlA = ltl[wbase + grp * 16 + col];
        float2 x01 = {0.f, 0.f}, x23 = {0.f, 0.f}, x45 = {0.f, 0.f};
        if (tlA != 0.f) {   // li < N0 guaranteed when tlA != 0
            int n = g * N0 + nbase + grp * 16 + col;
            const float2* xv = reinterpret_cast<const float2*>(x) + (size_t)n * 3;
            x01 = xv[0]; x23 = xv[1]; x45 = xv[2];
        }
        bf16x8 A0, A1;
#pragma unroll
        for (int j = 0; j < 8; j++) {
            int h0 = kb8 + j;
            int s0 = ((h0 >> 3) & 1) << 2;
            float4 wa = *reinterpret_cast<const float4*>(&sW1[(h0 * 8) ^ s0]);
            float4 wb = *reinterpret_cast<const float4*>(&sW1[(h0 * 8 + 4) ^ s0]);
            float a = wb.z;
            a += x01.x * wa.x; a += x01.y * wa.y;
            a += x23.x * wa.z; a += x23.y * wa.w;
            a += x45.x * wb.x; a += x45.y * wb.y;
            A0[j] = f2bf(tlA * fmaxf(a, 0.f));
            int h1i = 32 + h0;
            int s1 = ((h1i >> 3) & 1) << 2;
            float4 va = *reinterpret_cast<const float4*>(&sW1[(h1i * 8) ^ s1]);
            float4 vb = *reinterpret_cast<const float4*>(&sW1[(h1i * 8 + 4) ^ s1]);
            float b = vb.z;
            b += x01.x * va.x; b += x01.y * va.y;
            b += x23.x * va.z; b += x23.y * va.w;
            b += x45.x * vb.x; b += x45.y * vb.y;
            A1[j] = f2bf(tlA * fmaxf(b, 0.f));
        }
        f32x4 acc0 = {0.f, 0.f, 0.f, 0.f};
        f32x4 acc1 = {0.f, 0.f, 0.f, 0.f};
        acc0 = __builtin_amdgcn_mfma_f32_16x16x32_bf16(
            A0, *reinterpret_cast<const bf16x8*>(&sW2T[col * 72 + kb8]), acc0, 0, 0, 0);
        acc0 = __builtin_amdgcn_mfma_f32_16x16x32_bf16(
            A1, *reinterpret_cast<const bf16x8*>(&sW2T[col * 72 + 32 + kb8]), acc0, 0, 0, 0);
        acc1 = __builtin_amdgcn_mfma_f32_16x16x32_bf16(
            A0, *reinterpret_cast<const bf16x8*>(&sW2T[(col + 16) * 72 + kb8]), acc1, 0, 0, 0);
        acc1 = __builtin_amdgcn_mfma_f32_16x16x32_bf16(
            A1, *reinterpret_cast<const bf16x8*>(&sW2T[(col + 16) * 72 + 32 + kb8]), acc1, 0, 0, 0);
#pragma unroll
        for (int reg = 0; reg < 4; reg++) {
            float mr = lmk[wbase + grp * 16 + q * 4 + reg];
            rm0 = fmaxf(rm0, mr * fmaxf(acc0[reg] + b2c0, 0.f));
            rm1 = fmaxf(rm1, mr * fmaxf(acc1[reg] + b2c1, 0.f));
        }
    }
    rm0 = fmaxf(rm0, __shfl_xor(rm0, 16, 64));
    rm0 = fmaxf(rm0, __shfl_xor(rm0, 32, 64));
    rm1 = fmaxf(rm1, __shfl_xor(rm1, 16, 64));
    rm1 = fmaxf(rm1, __shfl_xor(rm1, 32, 64));
    if (lane < 16) {
        atomicMax((int*)&m[col], __float_as_int(rm0));
        atomicMax((int*)&m[col + 16], __float_as_int(rm1));
    }
    __syncthreads();
    if (tid < H2C) atomicMax((int*)&gmax[g * H2C + tid], __float_as_int(m[tid]));
}

// ---------- readout ----------
__global__ void k_final(const float* gmax, const float* Wf, const float* bf, float* out) {
    int g = threadIdx.x;
    if (g < BATCH) {
        float acc = bf[0];
        for (int c = 0; c < H2C; c++) acc += gmax[g * H2C + c] * Wf[c];
        out[g] = 1.f / (1.f + expf(-acc));
    }
}

extern "C" void kernel_launch(void* const* d_in, const int* in_sizes, int n_in,
                              void* d_out, int out_size, void* d_ws, size_t ws_size,
                              hipStream_t stream) {
    const float* data = (const float*)d_in[0];
    const void*  ei   = d_in[1];
    const float* W1   = (const float*)d_in[2];
    const float* b1   = (const float*)d_in[3];
    const float* Wp   = (const float*)d_in[4];
    const float* bp   = (const float*)d_in[5];
    const float* W2   = (const float*)d_in[6];
    const float* b2   = (const float*)d_in[7];
    const float* Wf   = (const float*)d_in[8];
    const float* bf   = (const float*)d_in[9];
    float* out = (float*)d_out;

    char* ws = (char*)d_ws;
    size_t off = 0;
    auto A = [&](size_t bytes) -> size_t {
        size_t o = off; off += (bytes + 511) & ~(size_t)511; return o;
    };
    // zero-initialized region (single memset)
    size_t o_deg0 = A((size_t)N0 * 4);
    size_t o_cnt  = A((size_t)N0 * 4);
    size_t o_gmax = A((size_t)BATCH * H2C * 4);
    size_t zbytes = off;
    // rest
    size_t o_src  = A((size_t)NE * 4);
    size_t o_dst  = A((size_t)NE * 4);
    size_t o_rp   = A((size_t)(N0 + 1) * 4);
    size_t o_csr  = A((size_t)NE * 4);
    size_t o_xw1  = A((size_t)N0 * H1C * 4);
    size_t o_h1   = A((size_t)N0 * H1C * 4);
    size_t o_di0  = A((size_t)N0 * 4);
    size_t o_di2  = A((size_t)N0 * 4);
    size_t o_h1w  = A((size_t)N0 * 4);
    size_t o_scr  = A((size_t)NT * 4);
    size_t o_sel  = A((size_t)NT);
    size_t o_xw2  = A((size_t)N0 * H2C * 4);
    size_t o_acc2 = A((size_t)N0 * H2C * 4);
    size_t o_flag = A(4);

    uint*  deg0 = (uint*)(ws + o_deg0);
    uint*  cnt  = (uint*)(ws + o_cnt);
    float* gmax = (float*)(ws + o_gmax);
    int*   src  = (int*)(ws + o_src);
    int*   dst  = (int*)(ws + o_dst);
    int*   rp   = (int*)(ws + o_rp);
    int*   csr  = (int*)(ws + o_csr);
    float* xw1  = (float*)(ws + o_xw1);
    float* h1   = (float*)(ws + o_h1);
    float* di0  = (float*)(ws + o_di0);
    float* di2  = (float*)(ws + o_di2);
    float* h1w  = (float*)(ws + o_h1w);
    float* scr  = (float*)(ws + o_scr);
    uchar* sel  = (uchar*)(ws + o_sel);
    float* xw2  = (float*)(ws + o_xw2);
    float* acc2 = (float*)(ws + o_acc2);
    int*   flag = (int*)(ws + o_flag);

    hipMemsetAsync(ws, 0, zbytes, stream);

    k_detect<<<1, 256, 0, stream>>>((const uint*)ei, flag);
    k_convert<<<2048, 256, 0, stream>>>(ei, flag, src, dst);
    k_deg<<<(NE + 255) / 256, 256, 0, stream>>>(dst, deg0);
    k_scan<<<1, 256, 0, stream>>>(deg0, rp);
    k_scatter<<<(NE + 255) / 256, 256, 0, stream>>>(src, dst, rp, cnt, csr);
    k_xw1<<<(N0 * H1C + 255) / 256, 256, 0, stream>>>(data, W1, xw1);
    k_dinv<<<(N0 + 255) / 256, 256, 0, stream>>>(deg0, di0);
    k_gath1<<<(N0 * 64 + 255) / 256, 256, 0, stream>>>(rp, csr, di0, xw1, b1, h1);
    k_h1w<<<(N0 + 255) / 256, 256, 0, stream>>>(h1, Wp, h1w);
    k_gscore0<<<(N0 + 255) / 256, 256, 0, stream>>>(rp, csr, di0, h1w, bp, scr);
    k_score_rest<<<(NT - N0 + 255) / 256, 256, 0, stream>>>(data, W1, b1, Wp, bp, scr);
    k_topk<<<BATCH, 256, 0, stream>>>(scr, sel);
    k_gdinv2<<<(N0 + 255) / 256, 256, 0, stream>>>(rp, csr, sel, di2);
    k_xw2<<<(N0 * H2C + 255) / 256, 256, 0, stream>>>(h1, scr, sel, W2, xw2);
    k_gath2<<<(N0 * 64 + 255) / 256, 256, 0, stream>>>(rp, csr, sel, di2, xw2, acc2);
    k_fin2<<<(N0 + 7) / 8, 256, 0, stream>>>(acc2, xw2, di2, sel, b2, gmax);
    k_rest_pool<<<(BATCH - 1) * BPGR, 256, 0, stream>>>(data, scr, sel, W1, b1, W2, b2, gmax);
    k_final<<<1, 64, 0, stream>>>(gmax, Wf, bf, out);
}

// Round 10
// 435.324 us; speedup vs baseline: 14.2850x; 1.2129x over previous
//
#include <hip/hip_runtime.h>
#include <hip/hip_bf16.h>
#include <math.h>

#define N0   17186
#define FIN  6
#define H1C  64
#define H2C  32
#define KSEL 12031
#define BATCH 64
#define NE   500000
#define NT   (BATCH * N0)

typedef unsigned int uint;
typedef unsigned char uchar;
typedef __attribute__((ext_vector_type(8))) short bf16x8;
typedef __attribute__((ext_vector_type(4))) float f32x4;

__device__ __forceinline__ uint keyOf(float f) {
    uint u = __float_as_uint(f);
    return (u & 0x80000000u) ? ~u : (u | 0x80000000u);
}

__device__ __forceinline__ short f2bf(float f) {
    union { __hip_bfloat16 b; short s; } u;
    u.b = __float2bfloat16(f);
    return u.s;
}

// ---------- edge dtype detection / normalization ----------
__global__ void k_detect(const uint* ei, int* flag64) {
    __shared__ int any;
    if (threadIdx.x == 0) any = 0;
    __syncthreads();
    for (int i = threadIdx.x; i < 1024; i += blockDim.x)
        if (ei[2 * i + 1] != 0u) any = 1;
    __syncthreads();
    if (threadIdx.x == 0) *flag64 = any ? 0 : 1;
}

__global__ void k_convert(const void* ei, const int* flag64, int* src, int* dst) {
    int f = *flag64;
    int stride = gridDim.x * blockDim.x;
    for (int i = blockIdx.x * blockDim.x + threadIdx.x; i < 2 * NE; i += stride) {
        int v = f ? (int)((const long long*)ei)[i] : ((const int*)ei)[i];
        if (i < NE) src[i] = v; else dst[i - NE] = v;
    }
}

// ---------- CSR build ----------
__global__ void k_deg(const int* dst, uint* deg) {
    int e = blockIdx.x * blockDim.x + threadIdx.x;
    if (e < NE) atomicAdd(&deg[dst[e]], 1u);
}

__global__ void k_scan(const uint* deg, int* rowptr) {
    __shared__ uint tsum[256];
    int tid = threadIdx.x;
    const int CH = (N0 + 255) / 256;  // 68
    int beg = tid * CH, end = beg + CH;
    if (end > N0) end = N0;
    uint s = 0;
    for (int i = beg; i < end; i++) s += deg[i];
    tsum[tid] = s;
    __syncthreads();
    for (int off = 1; off < 256; off <<= 1) {
        uint v = tsum[tid];
        uint a = (tid >= off) ? tsum[tid - off] : 0u;
        __syncthreads();
        tsum[tid] = v + a;
        __syncthreads();
    }
    uint run = (tid > 0) ? tsum[tid - 1] : 0u;
    for (int i = beg; i < end; i++) { rowptr[i] = (int)run; run += deg[i]; }
    if (tid == 255) rowptr[N0] = (int)run;
}

__global__ void k_scatter(const int* src, const int* dst, const int* rowptr,
                          uint* cnt, int* csr) {
    int e = blockIdx.x * blockDim.x + threadIdx.x;
    if (e < NE) {
        int d = dst[e];
        uint p = atomicAdd(&cnt[d], 1u);
        csr[rowptr[d] + (int)p] = src[e];
    }
}

// ---------- conv1 (graph 0) ----------
__global__ void k_xw1(const float* x, const float* W1, float* xw1) {
    int t = blockIdx.x * blockDim.x + threadIdx.x;
    if (t >= N0 * H1C) return;
    int i = t >> 6, h = t & 63;
    float acc = 0.f;
#pragma unroll
    for (int f = 0; f < FIN; f++) acc += x[i * FIN + f] * W1[f * H1C + h];
    xw1[t] = acc;
}

__global__ void k_dinv(const uint* deg, float* dinv) {
    int i = blockIdx.x * blockDim.x + threadIdx.x;
    if (i < N0) dinv[i] = rsqrtf(1.0f + (float)deg[i]);
}

// gather conv1 messages + finish h1 (fused fin1), 4-way unrolled
__global__ void k_gath1(const int* rowptr, const int* csr, const float* dinv,
                        const float* xw1, const float* b1, float* h1) {
    int wid = (blockIdx.x * blockDim.x + threadIdx.x) >> 6;
    int lane = threadIdx.x & 63;
    if (wid >= N0) return;
    int d = wid;
    int beg = rowptr[d], end = rowptr[d + 1];
    float a0 = 0.f, a1 = 0.f, a2 = 0.f, a3 = 0.f;
    int e = beg;
    for (; e + 4 <= end; e += 4) {
        int s0 = csr[e], s1 = csr[e + 1], s2 = csr[e + 2], s3 = csr[e + 3];
        a0 += xw1[(size_t)s0 * H1C + lane] * dinv[s0];
        a1 += xw1[(size_t)s1 * H1C + lane] * dinv[s1];
        a2 += xw1[(size_t)s2 * H1C + lane] * dinv[s2];
        a3 += xw1[(size_t)s3 * H1C + lane] * dinv[s3];
    }
    for (; e < end; e++) {
        int s = csr[e];
        a0 += xw1[(size_t)s * H1C + lane] * dinv[s];
    }
    float acc = (a0 + a1) + (a2 + a3);
    float did = dinv[d];
    float v = acc * did + xw1[(size_t)d * H1C + lane] * did * did + b1[lane];
    h1[(size_t)d * H1C + lane] = fmaxf(v, 0.f);
}

// ---------- pooling score ----------
__global__ void k_h1w(const float* h1, const float* Wp, float* h1w) {
    int i = blockIdx.x * blockDim.x + threadIdx.x;
    if (i >= N0) return;
    const float* row = h1 + (size_t)i * H1C;
    float acc = 0.f;
#pragma unroll
    for (int h = 0; h < H1C; h++) acc += row[h] * Wp[h];
    h1w[i] = acc;
}

// graph-0 score: gather + self-loop (fused smsg+score0)
__global__ void k_gscore0(const int* rowptr, const int* csr, const float* dinv,
                          const float* h1w, const float* bp, float* score) {
    int d = blockIdx.x * blockDim.x + threadIdx.x;
    if (d >= N0) return;
    float acc = 0.f;
    int beg = rowptr[d], end = rowptr[d + 1];
    for (int e = beg; e < end; e++) {
        int s = csr[e];
        acc += h1w[s] * dinv[s];
    }
    float did = dinv[d];
    score[d] = acc * did + h1w[d] * did * did + bp[0];
}

// graphs 1..63: score = relu(x@W1+b1) . Wp + bp
// Weights staged in LDS: sW[h*8] = {W1[0..5][h], b1[h], Wp[h]} (broadcast reads).
__global__ void k_score_rest(const float* __restrict__ x, const float* __restrict__ W1,
                             const float* __restrict__ b1, const float* __restrict__ Wp,
                             const float* __restrict__ bp, float* score) {
    __shared__ __align__(16) float sW[H1C * 8];
    int tid = threadIdx.x;
    if (tid < H1C) {
#pragma unroll
        for (int f = 0; f < FIN; f++) sW[tid * 8 + f] = W1[f * H1C + tid];
        sW[tid * 8 + 6] = b1[tid];
        sW[tid * 8 + 7] = Wp[tid];
    }
    __syncthreads();
    int idx = blockIdx.x * blockDim.x + tid;
    int n = N0 + idx;
    if (n >= NT) return;
    const float2* xv = reinterpret_cast<const float2*>(x) + (size_t)n * 3;
    float2 x01 = xv[0], x23 = xv[1], x45 = xv[2];
    float sc = bp[0];
#pragma unroll
    for (int h = 0; h < H1C; h++) {
        float4 wa = *reinterpret_cast<const float4*>(&sW[h * 8]);
        float4 wb = *reinterpret_cast<const float4*>(&sW[h * 8 + 4]);
        float a = wb.z;                       // b1[h]
        a += x01.x * wa.x; a += x01.y * wa.y;
        a += x23.x * wa.z; a += x23.y * wa.w;
        a += x45.x * wb.x; a += x45.y * wb.y;
        sc += fmaxf(a, 0.f) * wb.w;           // Wp[h]
    }
    score[n] = sc;
}

// ---------- per-graph top-K selection (radix select on float keys) ----------
__global__ void k_topk(const float* score, uchar* sel) {
    int g = blockIdx.x;
    const float* sc = score + (size_t)g * N0;
    uchar* sl = sel + (size_t)g * N0;
    __shared__ uint hist[4][256];
    __shared__ uint shPrefix, shWant;
    __shared__ uint wtot[4];
    int tid = threadIdx.x;
    int wave = tid >> 6, lane = tid & 63;
    uint prefix = 0, want = KSEL;
    for (int pass = 0; pass < 4; pass++) {
        int shift = 24 - 8 * pass;
#pragma unroll
        for (int w = 0; w < 4; w++) hist[w][tid] = 0;
        __syncthreads();
        for (int i = tid; i < N0; i += 256) {
            uint k = keyOf(sc[i]);
            bool active = (pass == 0) || ((k >> (shift + 8)) == prefix);
            if (active) atomicAdd(&hist[wave][(k >> shift) & 255], 1u);
        }
        __syncthreads();
        uint merged = hist[0][tid] + hist[1][tid] + hist[2][tid] + hist[3][tid];
        hist[0][tid] = merged;
        __syncthreads();
        if (tid == 0) {
            uint cum = 0; int d = 255;
            for (; d > 0; d--) { cum += hist[0][d]; if (cum >= want) break; }
            if (cum < want) cum += hist[0][0];        // d==0 fallthrough
            shWant = want - (cum - hist[0][d]);
            shPrefix = (prefix << 8) | (uint)d;
        }
        __syncthreads();
        prefix = shPrefix; want = shWant;
        __syncthreads();
    }
    uint T = prefix, needEq = want;
    uint runningEq = 0;
    for (int base = 0; base < N0; base += 256) {
        int i = base + tid;
        uint k = (i < N0) ? keyOf(sc[i]) : 0u;
        bool isEq = (i < N0) && (k == T);
        unsigned long long mask = __ballot(isEq);
        uint wprefix = (uint)__popcll(mask & ((1ull << lane) - 1ull));
        uint wcount = (uint)__popcll(mask);
        if (lane == 0) wtot[wave] = wcount;
        __syncthreads();
        uint before = 0;
#pragma unroll
        for (int w = 0; w < 4; w++) if (w < wave) before += wtot[w];
        uint total = wtot[0] + wtot[1] + wtot[2] + wtot[3];
        if (i < N0) {
            uchar s = 0;
            if (k > T) s = 1;
            else if (isEq && (runningEq + before + wprefix) < needEq) s = 1;
            sl[i] = s;
        }
        runningEq += total;
        __syncthreads();
    }
}

// ---------- conv2 (graph 0, selection-filtered) ----------
__global__ void k_gdinv2(const int* rowptr, const int* csr, const uchar* sel,
                         float* dinv2) {
    int d = blockIdx.x * blockDim.x + threadIdx.x;
    if (d >= N0) return;
    float r = 0.f;
    if (sel[d]) {
        int c = 0;
        int beg = rowptr[d], end = rowptr[d + 1];
        for (int e = beg; e < end; e++) c += sel[csr[e]];
        r = rsqrtf(1.f + (float)c);
    }
    dinv2[d] = r;
}

__global__ void k_xw2(const float* h1, const float* score, const uchar* sel,
                      const float* W2, float* xw2) {
    int gt = blockIdx.x * blockDim.x + threadIdx.x;
    int i = gt >> 5, c = gt & 31;
    if (i >= N0) return;
    if (!sel[i]) return;
    float t = tanhf(score[i]);
    const float* row = h1 + (size_t)i * H1C;
    float acc = 0.f;
#pragma unroll
    for (int h = 0; h < H1C; h++) acc += row[h] * W2[h * H2C + c];
    xw2[i * H2C + c] = acc * t;
}

__global__ void k_gath2(const int* rowptr, const int* csr, const uchar* sel,
                        const float* dinv2, const float* xw2, float* acc2) {
    int wid = (blockIdx.x * blockDim.x + threadIdx.x) >> 6;
    int lane = threadIdx.x & 63;
    if (wid >= N0) return;
    int d = wid;
    if (!sel[d]) return;
    int c = lane & 31;
    int beg = rowptr[d], end = rowptr[d + 1];
    float a0 = 0.f, a1 = 0.f;
    int e = beg + (lane >> 5);
    for (; e + 2 < end; e += 4) {   // this half-wave handles e, e+2
        int s0 = csr[e], s1 = csr[e + 2];
        a0 += xw2[(size_t)s0 * H2C + c] * dinv2[s0];
        a1 += xw2[(size_t)s1 * H2C + c] * dinv2[s1];
    }
    if (e < end) {
        int s = csr[e];
        a0 += xw2[(size_t)s * H2C + c] * dinv2[s];
    }
    float acc = a0 + a1;
    acc += __shfl_xor(acc, 32, 64);
    if (lane < 32) acc2[(size_t)d * H2C + c] = acc * dinv2[d];
}

__global__ void k_fin2(const float* acc2, const float* xw2, const float* dinv2,
                       const uchar* sel, const float* b2, float* gmax) {
    __shared__ float m[32];
    int tid = threadIdx.x;
    if (tid < 32) m[tid] = 0.f;
    __syncthreads();
    int i = blockIdx.x * 8 + (tid >> 5);
    int c = tid & 31;
    float v = 0.f;
    if (i < N0 && sel[i]) {
        float di = dinv2[i];
        v = fmaxf(acc2[(size_t)i * H2C + c] + xw2[(size_t)i * H2C + c] * di * di + b2[c], 0.f);
    }
    atomicMax((int*)&m[c], __float_as_int(v));
    __syncthreads();
    if (tid < 32) atomicMax((int*)&gmax[tid], __float_as_int(m[tid]));
}

// ---------- graphs 1..63: h2 + max pool, BOTH layers via MFMA (v4) ----------
// R9 root cause: scalar layer-1 (32 unrolled float4-LDS-read FMA chains) needs
// ~80 live VGPRs; allocator pins 64 -> per-grp scratch spill (159MB WRITE).
// v4: layer1 as MFMA with X~=[x,1] (K=32, zero-padded; bias = W1~ row 6):
//   A0 built by 8 register selects from x (q==0 lanes only), B1 frags from
//   global (persistent, 16 VGPR). 4 MFMAs -> h1[16 nodes][64ch]; tanh*relu,
//   ds_write_b16 into wave-private transpose buffer h1T[16][72] (16B rows,
//   <=2-way banks); layer2 A-frags = 2x ds_read_b128 from h1T; W2 from sW2T
//   as R9. Peak live ~50 VGPR < 64 -> spill structurally impossible.
//   Within-wave DS ordering (write->read same array) needs no barrier.
#define BPGR 68
__global__ __launch_bounds__(256, 2)
void k_rest_pool(const float* __restrict__ x, const float* __restrict__ score,
                 const uchar* __restrict__ sel,
                 const float* __restrict__ W1, const float* __restrict__ b1,
                 const float* __restrict__ W2, const float* __restrict__ b2,
                 float* gmax) {
    __shared__ __align__(16) short sW2T[H2C * 72];
    __shared__ __align__(16) short h1T[4][16 * 72];
    __shared__ float ltl[256];
    __shared__ float lmk[256];
    __shared__ float m[H2C];
    int tid = threadIdx.x;
    if (tid < H2C) m[tid] = 0.f;
    {   // W2^T bf16 staging: sW2T[c][k], row stride 72 shorts (144B)
        int c = tid >> 3, k0 = (tid & 7) * 8;
#pragma unroll
        for (int k = 0; k < 8; k++)
            sW2T[c * 72 + k0 + k] = f2bf(W2[(k0 + k) * H2C + c]);
    }
    int lane = tid & 63;
    int wv = tid >> 6;
    int g = blockIdx.x / BPGR + 1;
    int wslot = (blockIdx.x % BPGR) * 4 + wv;
    int nbase = wslot * 64;
    {   // per-node tanh / mask for this wave's 64 nodes
        int li = nbase + lane;
        bool inb = li < N0;
        int n = g * N0 + (inb ? li : 0);
        bool valid = inb && sel[n];
        ltl[tid] = valid ? tanhf(score[n]) : 0.f;
        lmk[tid] = valid ? 1.f : 0.f;
    }
    __syncthreads();

    int col = lane & 15;
    int q = lane >> 4;
    int kb8 = q * 8;
    int wbase = wv * 64;
    short* hrow = &h1T[wv][0];

    // Layer-1 B fragments: W1~[k][h], rows 0-5 = W1, row 6 = b1, rows 7..31 = 0.
    // Only q==0 lanes carry nonzero k (k = 0..7).
    bf16x8 B1a = {0, 0, 0, 0, 0, 0, 0, 0};
    bf16x8 B1b = {0, 0, 0, 0, 0, 0, 0, 0};
    bf16x8 B1c = {0, 0, 0, 0, 0, 0, 0, 0};
    bf16x8 B1d = {0, 0, 0, 0, 0, 0, 0, 0};
    if (q == 0) {
#pragma unroll
        for (int j = 0; j < 6; j++) {
            B1a[j] = f2bf(W1[j * H1C + col]);
            B1b[j] = f2bf(W1[j * H1C + 16 + col]);
            B1c[j] = f2bf(W1[j * H1C + 32 + col]);
            B1d[j] = f2bf(W1[j * H1C + 48 + col]);
        }
        B1a[6] = f2bf(b1[col]);
        B1b[6] = f2bf(b1[16 + col]);
        B1c[6] = f2bf(b1[32 + col]);
        B1d[6] = f2bf(b1[48 + col]);
    }
    float b2c0 = b2[col], b2c1 = b2[col + 16];

    float rm0 = 0.f, rm1 = 0.f;
#pragma unroll 1
    for (int grp = 0; grp < 4; grp++) {
        // ---- layer 1: A0 = X~ row for node nbase+grp*16+col (q==0 lanes) ----
        bf16x8 A0 = {0, 0, 0, 0, 0, 0, 0, 0};
        if (q == 0) {
            float tlc = ltl[wbase + grp * 16 + col];
            if (tlc != 0.f) {
                int n = g * N0 + nbase + grp * 16 + col;
                const float2* xv = reinterpret_cast<const float2*>(x) + (size_t)n * 3;
                float2 x01 = xv[0], x23 = xv[1], x45 = xv[2];
                A0[0] = f2bf(x01.x); A0[1] = f2bf(x01.y);
                A0[2] = f2bf(x23.x); A0[3] = f2bf(x23.y);
                A0[4] = f2bf(x45.x); A0[5] = f2bf(x45.y);
            }
            A0[6] = f2bf(1.0f);
        }
        float tn0 = ltl[wbase + grp * 16 + q * 4 + 0];
        float tn1 = ltl[wbase + grp * 16 + q * 4 + 1];
        float tn2 = ltl[wbase + grp * 16 + q * 4 + 2];
        float tn3 = ltl[wbase + grp * 16 + q * 4 + 3];
        // 4 h-blocks: mfma -> hv = tanh*relu -> transpose write (node-major)
        {
            f32x4 hz = {0.f, 0.f, 0.f, 0.f};
            f32x4 h = __builtin_amdgcn_mfma_f32_16x16x32_bf16(A0, B1a, hz, 0, 0, 0);
            hrow[(q * 4 + 0) * 72 + col]      = f2bf(tn0 * fmaxf(h[0], 0.f));
            hrow[(q * 4 + 1) * 72 + col]      = f2bf(tn1 * fmaxf(h[1], 0.f));
            hrow[(q * 4 + 2) * 72 + col]      = f2bf(tn2 * fmaxf(h[2], 0.f));
            hrow[(q * 4 + 3) * 72 + col]      = f2bf(tn3 * fmaxf(h[3], 0.f));
            h = __builtin_amdgcn_mfma_f32_16x16x32_bf16(A0, B1b, hz, 0, 0, 0);
            hrow[(q * 4 + 0) * 72 + 16 + col] = f2bf(tn0 * fmaxf(h[0], 0.f));
            hrow[(q * 4 + 1) * 72 + 16 + col] = f2bf(tn1 * fmaxf(h[1], 0.f));
            hrow[(q * 4 + 2) * 72 + 16 + col] = f2bf(tn2 * fmaxf(h[2], 0.f));
            hrow[(q * 4 + 3) * 72 + 16 + col] = f2bf(tn3 * fmaxf(h[3], 0.f));
            h = __builtin_amdgcn_mfma_f32_16x16x32_bf16(A0, B1c, hz, 0, 0, 0);
            hrow[(q * 4 + 0) * 72 + 32 + col] = f2bf(tn0 * fmaxf(h[0], 0.f));
            hrow[(q * 4 + 1) * 72 + 32 + col] = f2bf(tn1 * fmaxf(h[1], 0.f));
            hrow[(q * 4 + 2) * 72 + 32 + col] = f2bf(tn2 * fmaxf(h[2], 0.f));
            hrow[(q * 4 + 3) * 72 + 32 + col] = f2bf(tn3 * fmaxf(h[3], 0.f));
            h = __builtin_amdgcn_mfma_f32_16x16x32_bf16(A0, B1d, hz, 0, 0, 0);
            hrow[(q * 4 + 0) * 72 + 48 + col] = f2bf(tn0 * fmaxf(h[0], 0.f));
            hrow[(q * 4 + 1) * 72 + 48 + col] = f2bf(tn1 * fmaxf(h[1], 0.f));
            hrow[(q * 4 + 2) * 72 + 48 + col] = f2bf(tn2 * fmaxf(h[2], 0.f));
            hrow[(q * 4 + 3) * 72 + 48 + col] = f2bf(tn3 * fmaxf(h[3], 0.f));
        }
        // ---- layer 2: A-frags from transpose buffer, B from sW2T ----
        bf16x8 A2_0 = *reinterpret_cast<const bf16x8*>(&hrow[col * 72 + kb8]);
        bf16x8 A2_1 = *reinterpret_cast<const bf16x8*>(&hrow[col * 72 + 32 + kb8]);
        f32x4 acc0 = {0.f, 0.f, 0.f, 0.f};
        f32x4 acc1 = {0.f, 0.f, 0.f, 0.f};
        acc0 = __builtin_amdgcn_mfma_f32_16x16x32_bf16(
            A2_0, *reinterpret_cast<const bf16x8*>(&sW2T[col * 72 + kb8]), acc0, 0, 0, 0);
        acc0 = __builtin_amdgcn_mfma_f32_16x16x32_bf16(
            A2_1, *reinterpret_cast<const bf16x8*>(&sW2T[col * 72 + 32 + kb8]), acc0, 0, 0, 0);
        acc1 = __builtin_amdgcn_mfma_f32_16x16x32_bf16(
            A2_0, *reinterpret_cast<const bf16x8*>(&sW2T[(col + 16) * 72 + kb8]), acc1, 0, 0, 0);
        acc1 = __builtin_amdgcn_mfma_f32_16x16x32_bf16(
            A2_1, *reinterpret_cast<const bf16x8*>(&sW2T[(col + 16) * 72 + 32 + kb8]), acc1, 0, 0, 0);
        float mk0 = lmk[wbase + grp * 16 + q * 4 + 0];
        float mk1 = lmk[wbase + grp * 16 + q * 4 + 1];
        float mk2 = lmk[wbase + grp * 16 + q * 4 + 2];
        float mk3 = lmk[wbase + grp * 16 + q * 4 + 3];
        rm0 = fmaxf(rm0, mk0 * fmaxf(acc0[0] + b2c0, 0.f));
        rm0 = fmaxf(rm0, mk1 * fmaxf(acc0[1] + b2c0, 0.f));
        rm0 = fmaxf(rm0, mk2 * fmaxf(acc0[2] + b2c0, 0.f));
        rm0 = fmaxf(rm0, mk3 * fmaxf(acc0[3] + b2c0, 0.f));
        rm1 = fmaxf(rm1, mk0 * fmaxf(acc1[0] + b2c1, 0.f));
        rm1 = fmaxf(rm1, mk1 * fmaxf(acc1[1] + b2c1, 0.f));
        rm1 = fmaxf(rm1, mk2 * fmaxf(acc1[2] + b2c1, 0.f));
        rm1 = fmaxf(rm1, mk3 * fmaxf(acc1[3] + b2c1, 0.f));
    }
    rm0 = fmaxf(rm0, __shfl_xor(rm0, 16, 64));
    rm0 = fmaxf(rm0, __shfl_xor(rm0, 32, 64));
    rm1 = fmaxf(rm1, __shfl_xor(rm1, 16, 64));
    rm1 = fmaxf(rm1, __shfl_xor(rm1, 32, 64));
    if (lane < 16) {
        atomicMax((int*)&m[col], __float_as_int(rm0));
        atomicMax((int*)&m[col + 16], __float_as_int(rm1));
    }
    __syncthreads();
    if (tid < H2C) atomicMax((int*)&gmax[g * H2C + tid], __float_as_int(m[tid]));
}

// ---------- readout ----------
__global__ void k_final(const float* gmax, const float* Wf, const float* bf, float* out) {
    int g = threadIdx.x;
    if (g < BATCH) {
        float acc = bf[0];
        for (int c = 0; c < H2C; c++) acc += gmax[g * H2C + c] * Wf[c];
        out[g] = 1.f / (1.f + expf(-acc));
    }
}

extern "C" void kernel_launch(void* const* d_in, const int* in_sizes, int n_in,
                              void* d_out, int out_size, void* d_ws, size_t ws_size,
                              hipStream_t stream) {
    const float* data = (const float*)d_in[0];
    const void*  ei   = d_in[1];
    const float* W1   = (const float*)d_in[2];
    const float* b1   = (const float*)d_in[3];
    const float* Wp   = (const float*)d_in[4];
    const float* bp   = (const float*)d_in[5];
    const float* W2   = (const float*)d_in[6];
    const float* b2   = (const float*)d_in[7];
    const float* Wf   = (const float*)d_in[8];
    const float* bf   = (const float*)d_in[9];
    float* out = (float*)d_out;

    char* ws = (char*)d_ws;
    size_t off = 0;
    auto A = [&](size_t bytes) -> size_t {
        size_t o = off; off += (bytes + 511) & ~(size_t)511; return o;
    };
    // zero-initialized region (single memset)
    size_t o_deg0 = A((size_t)N0 * 4);
    size_t o_cnt  = A((size_t)N0 * 4);
    size_t o_gmax = A((size_t)BATCH * H2C * 4);
    size_t zbytes = off;
    // rest
    size_t o_src  = A((size_t)NE * 4);
    size_t o_dst  = A((size_t)NE * 4);
    size_t o_rp   = A((size_t)(N0 + 1) * 4);
    size_t o_csr  = A((size_t)NE * 4);
    size_t o_xw1  = A((size_t)N0 * H1C * 4);
    size_t o_h1   = A((size_t)N0 * H1C * 4);
    size_t o_di0  = A((size_t)N0 * 4);
    size_t o_di2  = A((size_t)N0 * 4);
    size_t o_h1w  = A((size_t)N0 * 4);
    size_t o_scr  = A((size_t)NT * 4);
    size_t o_sel  = A((size_t)NT);
    size_t o_xw2  = A((size_t)N0 * H2C * 4);
    size_t o_acc2 = A((size_t)N0 * H2C * 4);
    size_t o_flag = A(4);

    uint*  deg0 = (uint*)(ws + o_deg0);
    uint*  cnt  = (uint*)(ws + o_cnt);
    float* gmax = (float*)(ws + o_gmax);
    int*   src  = (int*)(ws + o_src);
    int*   dst  = (int*)(ws + o_dst);
    int*   rp   = (int*)(ws + o_rp);
    int*   csr  = (int*)(ws + o_csr);
    float* xw1  = (float*)(ws + o_xw1);
    float* h1   = (float*)(ws + o_h1);
    float* di0  = (float*)(ws + o_di0);
    float* di2  = (float*)(ws + o_di2);
    float* h1w  = (float*)(ws + o_h1w);
    float* scr  = (float*)(ws + o_scr);
    uchar* sel  = (uchar*)(ws + o_sel);
    float* xw2  = (float*)(ws + o_xw2);
    float* acc2 = (float*)(ws + o_acc2);
    int*   flag = (int*)(ws + o_flag);

    hipMemsetAsync(ws, 0, zbytes, stream);

    k_detect<<<1, 256, 0, stream>>>((const uint*)ei, flag);
    k_convert<<<2048, 256, 0, stream>>>(ei, flag, src, dst);
    k_deg<<<(NE + 255) / 256, 256, 0, stream>>>(dst, deg0);
    k_scan<<<1, 256, 0, stream>>>(deg0, rp);
    k_scatter<<<(NE + 255) / 256, 256, 0, stream>>>(src, dst, rp, cnt, csr);
    k_xw1<<<(N0 * H1C + 255) / 256, 256, 0, stream>>>(data, W1, xw1);
    k_dinv<<<(N0 + 255) / 256, 256, 0, stream>>>(deg0, di0);
    k_gath1<<<(N0 * 64 + 255) / 256, 256, 0, stream>>>(rp, csr, di0, xw1, b1, h1);
    k_h1w<<<(N0 + 255) / 256, 256, 0, stream>>>(h1, Wp, h1w);
    k_gscore0<<<(N0 + 255) / 256, 256, 0, stream>>>(rp, csr, di0, h1w, bp, scr);
    k_score_rest<<<(NT - N0 + 255) / 256, 256, 0, stream>>>(data, W1, b1, Wp, bp, scr);
    k_topk<<<BATCH, 256, 0, stream>>>(scr, sel);
    k_gdinv2<<<(N0 + 255) / 256, 256, 0, stream>>>(rp, csr, sel, di2);
    k_xw2<<<(N0 * H2C + 255) / 256, 256, 0, stream>>>(h1, scr, sel, W2, xw2);
    k_gath2<<<(N0 * 64 + 255) / 256, 256, 0, stream>>>(rp, csr, sel, di2, xw2, acc2);
    k_fin2<<<(N0 + 7) / 8, 256, 0, stream>>>(acc2, xw2, di2, sel, b2, gmax);
    k_rest_pool<<<(BATCH - 1) * BPGR, 256, 0, stream>>>(data, scr, sel, W1, b1, W2, b2, gmax);
    k_final<<<1, 64, 0, stream>>>(gmax, Wf, bf, out);
}

// Round 11
// 385.944 us; speedup vs baseline: 16.1128x; 1.1279x over previous
//
#include <hip/hip_runtime.h>
#include <hip/hip_bf16.h>
#include <math.h>

#define N0   17186
#define FIN  6
#define H1C  64
#define H2C  32
#define KSEL 12031
#define BATCH 64
#define NE   500000
#define NT   (BATCH * N0)

typedef unsigned int uint;
typedef unsigned char uchar;
typedef __attribute__((ext_vector_type(8))) short bf16x8;
typedef __attribute__((ext_vector_type(4))) float f32x4;

__device__ __forceinline__ uint keyOf(float f) {
    uint u = __float_as_uint(f);
    return (u & 0x80000000u) ? ~u : (u | 0x80000000u);
}

__device__ __forceinline__ short f2bf(float f) {
    union { __hip_bfloat16 b; short s; } u;
    u.b = __float2bfloat16(f);
    return u.s;
}

// ---------- edge dtype detection / normalization ----------
__global__ void k_detect(const uint* ei, int* flag64) {
    __shared__ int any;
    if (threadIdx.x == 0) any = 0;
    __syncthreads();
    for (int i = threadIdx.x; i < 1024; i += blockDim.x)
        if (ei[2 * i + 1] != 0u) any = 1;
    __syncthreads();
    if (threadIdx.x == 0) *flag64 = any ? 0 : 1;
}

__global__ void k_convert(const void* ei, const int* flag64, int* src, int* dst) {
    int f = *flag64;
    int stride = gridDim.x * blockDim.x;
    for (int i = blockIdx.x * blockDim.x + threadIdx.x; i < 2 * NE; i += stride) {
        int v = f ? (int)((const long long*)ei)[i] : ((const int*)ei)[i];
        if (i < NE) src[i] = v; else dst[i - NE] = v;
    }
}

// ---------- CSR build ----------
__global__ void k_deg(const int* dst, uint* deg) {
    int e = blockIdx.x * blockDim.x + threadIdx.x;
    if (e < NE) atomicAdd(&deg[dst[e]], 1u);
}

__global__ void k_scan(const uint* deg, int* rowptr) {
    __shared__ uint tsum[256];
    int tid = threadIdx.x;
    const int CH = (N0 + 255) / 256;  // 68
    int beg = tid * CH, end = beg + CH;
    if (end > N0) end = N0;
    uint s = 0;
    for (int i = beg; i < end; i++) s += deg[i];
    tsum[tid] = s;
    __syncthreads();
    for (int off = 1; off < 256; off <<= 1) {
        uint v = tsum[tid];
        uint a = (tid >= off) ? tsum[tid - off] : 0u;
        __syncthreads();
        tsum[tid] = v + a;
        __syncthreads();
    }
    uint run = (tid > 0) ? tsum[tid - 1] : 0u;
    for (int i = beg; i < end; i++) { rowptr[i] = (int)run; run += deg[i]; }
    if (tid == 255) rowptr[N0] = (int)run;
}

__global__ void k_scatter(const int* src, const int* dst, const int* rowptr,
                          uint* cnt, int* csr) {
    int e = blockIdx.x * blockDim.x + threadIdx.x;
    if (e < NE) {
        int d = dst[e];
        uint p = atomicAdd(&cnt[d], 1u);
        csr[rowptr[d] + (int)p] = src[e];
    }
}

// ---------- conv1 (graph 0) ----------
__global__ void k_xw1(const float* x, const float* W1, float* xw1) {
    int t = blockIdx.x * blockDim.x + threadIdx.x;
    if (t >= N0 * H1C) return;
    int i = t >> 6, h = t & 63;
    float acc = 0.f;
#pragma unroll
    for (int f = 0; f < FIN; f++) acc += x[i * FIN + f] * W1[f * H1C + h];
    xw1[t] = acc;
}

__global__ void k_dinv(const uint* deg, float* dinv) {
    int i = blockIdx.x * blockDim.x + threadIdx.x;
    if (i < N0) dinv[i] = rsqrtf(1.0f + (float)deg[i]);
}

// gather conv1 messages + finish h1 (fused fin1), 4-way unrolled
__global__ void k_gath1(const int* rowptr, const int* csr, const float* dinv,
                        const float* xw1, const float* b1, float* h1) {
    int wid = (blockIdx.x * blockDim.x + threadIdx.x) >> 6;
    int lane = threadIdx.x & 63;
    if (wid >= N0) return;
    int d = wid;
    int beg = rowptr[d], end = rowptr[d + 1];
    float a0 = 0.f, a1 = 0.f, a2 = 0.f, a3 = 0.f;
    int e = beg;
    for (; e + 4 <= end; e += 4) {
        int s0 = csr[e], s1 = csr[e + 1], s2 = csr[e + 2], s3 = csr[e + 3];
        a0 += xw1[(size_t)s0 * H1C + lane] * dinv[s0];
        a1 += xw1[(size_t)s1 * H1C + lane] * dinv[s1];
        a2 += xw1[(size_t)s2 * H1C + lane] * dinv[s2];
        a3 += xw1[(size_t)s3 * H1C + lane] * dinv[s3];
    }
    for (; e < end; e++) {
        int s = csr[e];
        a0 += xw1[(size_t)s * H1C + lane] * dinv[s];
    }
    float acc = (a0 + a1) + (a2 + a3);
    float did = dinv[d];
    float v = acc * did + xw1[(size_t)d * H1C + lane] * did * did + b1[lane];
    h1[(size_t)d * H1C + lane] = fmaxf(v, 0.f);
}

// ---------- pooling score ----------
__global__ void k_h1w(const float* h1, const float* Wp, float* h1w) {
    int i = blockIdx.x * blockDim.x + threadIdx.x;
    if (i >= N0) return;
    const float* row = h1 + (size_t)i * H1C;
    float acc = 0.f;
#pragma unroll
    for (int h = 0; h < H1C; h++) acc += row[h] * Wp[h];
    h1w[i] = acc;
}

// graph-0 score: gather + self-loop (fused smsg+score0)
__global__ void k_gscore0(const int* rowptr, const int* csr, const float* dinv,
                          const float* h1w, const float* bp, float* score) {
    int d = blockIdx.x * blockDim.x + threadIdx.x;
    if (d >= N0) return;
    float acc = 0.f;
    int beg = rowptr[d], end = rowptr[d + 1];
    for (int e = beg; e < end; e++) {
        int s = csr[e];
        acc += h1w[s] * dinv[s];
    }
    float did = dinv[d];
    score[d] = acc * did + h1w[d] * did * did + bp[0];
}

// graphs 1..63: score = relu(x@W1+b1) . Wp + bp
// Weights staged in LDS: sW[h*8] = {W1[0..5][h], b1[h], Wp[h]} (broadcast reads).
__global__ void k_score_rest(const float* __restrict__ x, const float* __restrict__ W1,
                             const float* __restrict__ b1, const float* __restrict__ Wp,
                             const float* __restrict__ bp, float* score) {
    __shared__ __align__(16) float sW[H1C * 8];
    int tid = threadIdx.x;
    if (tid < H1C) {
#pragma unroll
        for (int f = 0; f < FIN; f++) sW[tid * 8 + f] = W1[f * H1C + tid];
        sW[tid * 8 + 6] = b1[tid];
        sW[tid * 8 + 7] = Wp[tid];
    }
    __syncthreads();
    int idx = blockIdx.x * blockDim.x + tid;
    int n = N0 + idx;
    if (n >= NT) return;
    const float2* xv = reinterpret_cast<const float2*>(x) + (size_t)n * 3;
    float2 x01 = xv[0], x23 = xv[1], x45 = xv[2];
    float sc = bp[0];
#pragma unroll
    for (int h = 0; h < H1C; h++) {
        float4 wa = *reinterpret_cast<const float4*>(&sW[h * 8]);
        float4 wb = *reinterpret_cast<const float4*>(&sW[h * 8 + 4]);
        float a = wb.z;                       // b1[h]
        a += x01.x * wa.x; a += x01.y * wa.y;
        a += x23.x * wa.z; a += x23.y * wa.w;
        a += x45.x * wb.x; a += x45.y * wb.y;
        sc += fmaxf(a, 0.f) * wb.w;           // Wp[h]
    }
    score[n] = sc;
}

// ---------- per-graph top-K selection (radix select, v2) ----------
// R10: was 1 wave/SIMD latency-bound (105us, VALUBusy 1.8%, Occ 2.5%).
// v2: 1024 thr/block (16 waves -> 4/SIMD latency hiding), float4 score
// reads in histogram passes, per-wave hist[16][256] (16KB LDS), 16-wave
// stable tail scan. Selection semantics identical.
__global__ __launch_bounds__(1024)
void k_topk(const float* __restrict__ score, uchar* __restrict__ sel) {
    int g = blockIdx.x;
    const float* sc = score + (size_t)g * N0;
    uchar* sl = sel + (size_t)g * N0;
    __shared__ uint hist[16][256];
    __shared__ uint shPrefix, shWant;
    __shared__ uint wtot[16];
    int tid = threadIdx.x;
    int wave = tid >> 6, lane = tid & 63;
    uint prefix = 0, want = KSEL;
    const int N4 = N0 >> 2;                 // 4296 float4s, remainder 2
    const float4* sc4 = reinterpret_cast<const float4*>(sc);
    for (int pass = 0; pass < 4; pass++) {
        int shift = 24 - 8 * pass;
        for (int i = tid; i < 16 * 256; i += 1024) ((uint*)hist)[i] = 0;
        __syncthreads();
        uint* hw = hist[wave];
        for (int i = tid; i < N4; i += 1024) {
            float4 v = sc4[i];
            uint k0 = keyOf(v.x), k1 = keyOf(v.y), k2 = keyOf(v.z), k3 = keyOf(v.w);
            if (pass == 0) {
                atomicAdd(&hw[k0 >> 24], 1u);
                atomicAdd(&hw[k1 >> 24], 1u);
                atomicAdd(&hw[k2 >> 24], 1u);
                atomicAdd(&hw[k3 >> 24], 1u);
            } else {
                if ((k0 >> (shift + 8)) == prefix) atomicAdd(&hw[(k0 >> shift) & 255], 1u);
                if ((k1 >> (shift + 8)) == prefix) atomicAdd(&hw[(k1 >> shift) & 255], 1u);
                if ((k2 >> (shift + 8)) == prefix) atomicAdd(&hw[(k2 >> shift) & 255], 1u);
                if ((k3 >> (shift + 8)) == prefix) atomicAdd(&hw[(k3 >> shift) & 255], 1u);
            }
        }
        if (tid < 2) {      // N0 remainder elements
            uint k = keyOf(sc[N4 * 4 + tid]);
            bool active = (pass == 0) || ((k >> (shift + 8)) == prefix);
            if (active) atomicAdd(&hist[0][(k >> shift) & 255], 1u);
        }
        __syncthreads();
        if (tid < 256) {
            uint s = 0;
#pragma unroll
            for (int w = 0; w < 16; w++) s += hist[w][tid];
            hist[0][tid] = s;
        }
        __syncthreads();
        if (tid == 0) {
            uint cum = 0; int d = 255;
            for (; d > 0; d--) { cum += hist[0][d]; if (cum >= want) break; }
            if (cum < want) cum += hist[0][0];        // d==0 fallthrough
            shWant = want - (cum - hist[0][d]);
            shPrefix = (prefix << 8) | (uint)d;
        }
        __syncthreads();
        prefix = shPrefix; want = shWant;
        __syncthreads();
    }
    uint T = prefix, needEq = want;
    uint runningEq = 0;
    for (int base = 0; base < N0; base += 1024) {
        int i = base + tid;
        uint k = (i < N0) ? keyOf(sc[i]) : 0u;
        bool isEq = (i < N0) && (k == T);
        unsigned long long mask = __ballot(isEq);
        uint wprefix = (uint)__popcll(mask & ((1ull << lane) - 1ull));
        uint wcount = (uint)__popcll(mask);
        if (lane == 0) wtot[wave] = wcount;
        __syncthreads();
        uint before = 0, total = 0;
#pragma unroll
        for (int w = 0; w < 16; w++) {
            uint c = wtot[w];
            if (w < wave) before += c;
            total += c;
        }
        if (i < N0) {
            uchar s = 0;
            if (k > T) s = 1;
            else if (isEq && (runningEq + before + wprefix) < needEq) s = 1;
            sl[i] = s;
        }
        runningEq += total;
        __syncthreads();
    }
}

// ---------- conv2 (graph 0, selection-filtered) ----------
__global__ void k_gdinv2(const int* rowptr, const int* csr, const uchar* sel,
                         float* dinv2) {
    int d = blockIdx.x * blockDim.x + threadIdx.x;
    if (d >= N0) return;
    float r = 0.f;
    if (sel[d]) {
        int c = 0;
        int beg = rowptr[d], end = rowptr[d + 1];
        for (int e = beg; e < end; e++) c += sel[csr[e]];
        r = rsqrtf(1.f + (float)c);
    }
    dinv2[d] = r;
}

__global__ void k_xw2(const float* h1, const float* score, const uchar* sel,
                      const float* W2, float* xw2) {
    int gt = blockIdx.x * blockDim.x + threadIdx.x;
    int i = gt >> 5, c = gt & 31;
    if (i >= N0) return;
    if (!sel[i]) return;
    float t = tanhf(score[i]);
    const float* row = h1 + (size_t)i * H1C;
    float acc = 0.f;
#pragma unroll
    for (int h = 0; h < H1C; h++) acc += row[h] * W2[h * H2C + c];
    xw2[i * H2C + c] = acc * t;
}

__global__ void k_gath2(const int* rowptr, const int* csr, const uchar* sel,
                        const float* dinv2, const float* xw2, float* acc2) {
    int wid = (blockIdx.x * blockDim.x + threadIdx.x) >> 6;
    int lane = threadIdx.x & 63;
    if (wid >= N0) return;
    int d = wid;
    if (!sel[d]) return;
    int c = lane & 31;
    int beg = rowptr[d], end = rowptr[d + 1];
    float a0 = 0.f, a1 = 0.f;
    int e = beg + (lane >> 5);
    for (; e + 2 < end; e += 4) {   // this half-wave handles e, e+2
        int s0 = csr[e], s1 = csr[e + 2];
        a0 += xw2[(size_t)s0 * H2C + c] * dinv2[s0];
        a1 += xw2[(size_t)s1 * H2C + c] * dinv2[s1];
    }
    if (e < end) {
        int s = csr[e];
        a0 += xw2[(size_t)s * H2C + c] * dinv2[s];
    }
    float acc = a0 + a1;
    acc += __shfl_xor(acc, 32, 64);
    if (lane < 32) acc2[(size_t)d * H2C + c] = acc * dinv2[d];
}

__global__ void k_fin2(const float* acc2, const float* xw2, const float* dinv2,
                       const uchar* sel, const float* b2, float* gmax) {
    __shared__ float m[32];
    int tid = threadIdx.x;
    if (tid < 32) m[tid] = 0.f;
    __syncthreads();
    int i = blockIdx.x * 8 + (tid >> 5);
    int c = tid & 31;
    float v = 0.f;
    if (i < N0 && sel[i]) {
        float di = dinv2[i];
        v = fmaxf(acc2[(size_t)i * H2C + c] + xw2[(size_t)i * H2C + c] * di * di + b2[c], 0.f);
    }
    atomicMax((int*)&m[c], __float_as_int(v));
    __syncthreads();
    if (tid < 32) atomicMax((int*)&gmax[tid], __float_as_int(m[tid]));
}

// ---------- graphs 1..63: h2 + max pool, BOTH layers via MFMA (v4) ----------
#define BPGR 68
__global__ __launch_bounds__(256, 2)
void k_rest_pool(const float* __restrict__ x, const float* __restrict__ score,
                 const uchar* __restrict__ sel,
                 const float* __restrict__ W1, const float* __restrict__ b1,
                 const float* __restrict__ W2, const float* __restrict__ b2,
                 float* gmax) {
    __shared__ __align__(16) short sW2T[H2C * 72];
    __shared__ __align__(16) short h1T[4][16 * 72];
    __shared__ float ltl[256];
    __shared__ float lmk[256];
    __shared__ float m[H2C];
    int tid = threadIdx.x;
    if (tid < H2C) m[tid] = 0.f;
    {   // W2^T bf16 staging: sW2T[c][k], row stride 72 shorts (144B)
        int c = tid >> 3, k0 = (tid & 7) * 8;
#pragma unroll
        for (int k = 0; k < 8; k++)
            sW2T[c * 72 + k0 + k] = f2bf(W2[(k0 + k) * H2C + c]);
    }
    int lane = tid & 63;
    int wv = tid >> 6;
    int g = blockIdx.x / BPGR + 1;
    int wslot = (blockIdx.x % BPGR) * 4 + wv;
    int nbase = wslot * 64;
    {   // per-node tanh / mask for this wave's 64 nodes
        int li = nbase + lane;
        bool inb = li < N0;
        int n = g * N0 + (inb ? li : 0);
        bool valid = inb && sel[n];
        ltl[tid] = valid ? tanhf(score[n]) : 0.f;
        lmk[tid] = valid ? 1.f : 0.f;
    }
    __syncthreads();

    int col = lane & 15;
    int q = lane >> 4;
    int kb8 = q * 8;
    int wbase = wv * 64;
    short* hrow = &h1T[wv][0];

    // Layer-1 B fragments: W1~[k][h], rows 0-5 = W1, row 6 = b1, rows 7..31 = 0.
    bf16x8 B1a = {0, 0, 0, 0, 0, 0, 0, 0};
    bf16x8 B1b = {0, 0, 0, 0, 0, 0, 0, 0};
    bf16x8 B1c = {0, 0, 0, 0, 0, 0, 0, 0};
    bf16x8 B1d = {0, 0, 0, 0, 0, 0, 0, 0};
    if (q == 0) {
#pragma unroll
        for (int j = 0; j < 6; j++) {
            B1a[j] = f2bf(W1[j * H1C + col]);
            B1b[j] = f2bf(W1[j * H1C + 16 + col]);
            B1c[j] = f2bf(W1[j * H1C + 32 + col]);
            B1d[j] = f2bf(W1[j * H1C + 48 + col]);
        }
        B1a[6] = f2bf(b1[col]);
        B1b[6] = f2bf(b1[16 + col]);
        B1c[6] = f2bf(b1[32 + col]);
        B1d[6] = f2bf(b1[48 + col]);
    }
    float b2c0 = b2[col], b2c1 = b2[col + 16];

    float rm0 = 0.f, rm1 = 0.f;
#pragma unroll 1
    for (int grp = 0; grp < 4; grp++) {
        bf16x8 A0 = {0, 0, 0, 0, 0, 0, 0, 0};
        if (q == 0) {
            float tlc = ltl[wbase + grp * 16 + col];
            if (tlc != 0.f) {
                int n = g * N0 + nbase + grp * 16 + col;
                const float2* xv = reinterpret_cast<const float2*>(x) + (size_t)n * 3;
                float2 x01 = xv[0], x23 = xv[1], x45 = xv[2];
                A0[0] = f2bf(x01.x); A0[1] = f2bf(x01.y);
                A0[2] = f2bf(x23.x); A0[3] = f2bf(x23.y);
                A0[4] = f2bf(x45.x); A0[5] = f2bf(x45.y);
            }
            A0[6] = f2bf(1.0f);
        }
        float tn0 = ltl[wbase + grp * 16 + q * 4 + 0];
        float tn1 = ltl[wbase + grp * 16 + q * 4 + 1];
        float tn2 = ltl[wbase + grp * 16 + q * 4 + 2];
        float tn3 = ltl[wbase + grp * 16 + q * 4 + 3];
        {
            f32x4 hz = {0.f, 0.f, 0.f, 0.f};
            f32x4 h = __builtin_amdgcn_mfma_f32_16x16x32_bf16(A0, B1a, hz, 0, 0, 0);
            hrow[(q * 4 + 0) * 72 + col]      = f2bf(tn0 * fmaxf(h[0], 0.f));
            hrow[(q * 4 + 1) * 72 + col]      = f2bf(tn1 * fmaxf(h[1], 0.f));
            hrow[(q * 4 + 2) * 72 + col]      = f2bf(tn2 * fmaxf(h[2], 0.f));
            hrow[(q * 4 + 3) * 72 + col]      = f2bf(tn3 * fmaxf(h[3], 0.f));
            h = __builtin_amdgcn_mfma_f32_16x16x32_bf16(A0, B1b, hz, 0, 0, 0);
            hrow[(q * 4 + 0) * 72 + 16 + col] = f2bf(tn0 * fmaxf(h[0], 0.f));
            hrow[(q * 4 + 1) * 72 + 16 + col] = f2bf(tn1 * fmaxf(h[1], 0.f));
            hrow[(q * 4 + 2) * 72 + 16 + col] = f2bf(tn2 * fmaxf(h[2], 0.f));
            hrow[(q * 4 + 3) * 72 + 16 + col] = f2bf(tn3 * fmaxf(h[3], 0.f));
            h = __builtin_amdgcn_mfma_f32_16x16x32_bf16(A0, B1c, hz, 0, 0, 0);
            hrow[(q * 4 + 0) * 72 + 32 + col] = f2bf(tn0 * fmaxf(h[0], 0.f));
            hrow[(q * 4 + 1) * 72 + 32 + col] = f2bf(tn1 * fmaxf(h[1], 0.f));
            hrow[(q * 4 + 2) * 72 + 32 + col] = f2bf(tn2 * fmaxf(h[2], 0.f));
            hrow[(q * 4 + 3) * 72 + 32 + col] = f2bf(tn3 * fmaxf(h[3], 0.f));
            h = __builtin_amdgcn_mfma_f32_16x16x32_bf16(A0, B1d, hz, 0, 0, 0);
            hrow[(q * 4 + 0) * 72 + 48 + col] = f2bf(tn0 * fmaxf(h[0], 0.f));
            hrow[(q * 4 + 1) * 72 + 48 + col] = f2bf(tn1 * fmaxf(h[1], 0.f));
            hrow[(q * 4 + 2) * 72 + 48 + col] = f2bf(tn2 * fmaxf(h[2], 0.f));
            hrow[(q * 4 + 3) * 72 + 48 + col] = f2bf(tn3 * fmaxf(h[3], 0.f));
        }
        bf16x8 A2_0 = *reinterpret_cast<const bf16x8*>(&hrow[col * 72 + kb8]);
        bf16x8 A2_1 = *reinterpret_cast<const bf16x8*>(&hrow[col * 72 + 32 + kb8]);
        f32x4 acc0 = {0.f, 0.f, 0.f, 0.f};
        f32x4 acc1 = {0.f, 0.f, 0.f, 0.f};
        acc0 = __builtin_amdgcn_mfma_f32_16x16x32_bf16(
            A2_0, *reinterpret_cast<const bf16x8*>(&sW2T[col * 72 + kb8]), acc0, 0, 0, 0);
        acc0 = __builtin_amdgcn_mfma_f32_16x16x32_bf16(
            A2_1, *reinterpret_cast<const bf16x8*>(&sW2T[col * 72 + 32 + kb8]), acc0, 0, 0, 0);
        acc1 = __builtin_amdgcn_mfma_f32_16x16x32_bf16(
            A2_0, *reinterpret_cast<const bf16x8*>(&sW2T[(col + 16) * 72 + kb8]), acc1, 0, 0, 0);
        acc1 = __builtin_amdgcn_mfma_f32_16x16x32_bf16(
            A2_1, *reinterpret_cast<const bf16x8*>(&sW2T[(col + 16) * 72 + 32 + kb8]), acc1, 0, 0, 0);
        float mk0 = lmk[wbase + grp * 16 + q * 4 + 0];
        float mk1 = lmk[wbase + grp * 16 + q * 4 + 1];
        float mk2 = lmk[wbase + grp * 16 + q * 4 + 2];
        float mk3 = lmk[wbase + grp * 16 + q * 4 + 3];
        rm0 = fmaxf(rm0, mk0 * fmaxf(acc0[0] + b2c0, 0.f));
        rm0 = fmaxf(rm0, mk1 * fmaxf(acc0[1] + b2c0, 0.f));
        rm0 = fmaxf(rm0, mk2 * fmaxf(acc0[2] + b2c0, 0.f));
        rm0 = fmaxf(rm0, mk3 * fmaxf(acc0[3] + b2c0, 0.f));
        rm1 = fmaxf(rm1, mk0 * fmaxf(acc1[0] + b2c1, 0.f));
        rm1 = fmaxf(rm1, mk1 * fmaxf(acc1[1] + b2c1, 0.f));
        rm1 = fmaxf(rm1, mk2 * fmaxf(acc1[2] + b2c1, 0.f));
        rm1 = fmaxf(rm1, mk3 * fmaxf(acc1[3] + b2c1, 0.f));
    }
    rm0 = fmaxf(rm0, __shfl_xor(rm0, 16, 64));
    rm0 = fmaxf(rm0, __shfl_xor(rm0, 32, 64));
    rm1 = fmaxf(rm1, __shfl_xor(rm1, 16, 64));
    rm1 = fmaxf(rm1, __shfl_xor(rm1, 32, 64));
    if (lane < 16) {
        atomicMax((int*)&m[col], __float_as_int(rm0));
        atomicMax((int*)&m[col + 16], __float_as_int(rm1));
    }
    __syncthreads();
    if (tid < H2C) atomicMax((int*)&gmax[g * H2C + tid], __float_as_int(m[tid]));
}

// ---------- readout ----------
__global__ void k_final(const float* gmax, const float* Wf, const float* bf, float* out) {
    int g = threadIdx.x;
    if (g < BATCH) {
        float acc = bf[0];
        for (int c = 0; c < H2C; c++) acc += gmax[g * H2C + c] * Wf[c];
        out[g] = 1.f / (1.f + expf(-acc));
    }
}

extern "C" void kernel_launch(void* const* d_in, const int* in_sizes, int n_in,
                              void* d_out, int out_size, void* d_ws, size_t ws_size,
                              hipStream_t stream) {
    const float* data = (const float*)d_in[0];
    const void*  ei   = d_in[1];
    const float* W1   = (const float*)d_in[2];
    const float* b1   = (const float*)d_in[3];
    const float* Wp   = (const float*)d_in[4];
    const float* bp   = (const float*)d_in[5];
    const float* W2   = (const float*)d_in[6];
    const float* b2   = (const float*)d_in[7];
    const float* Wf   = (const float*)d_in[8];
    const float* bf   = (const float*)d_in[9];
    float* out = (float*)d_out;

    char* ws = (char*)d_ws;
    size_t off = 0;
    auto A = [&](size_t bytes) -> size_t {
        size_t o = off; off += (bytes + 511) & ~(size_t)511; return o;
    };
    // zero-initialized region (single memset)
    size_t o_deg0 = A((size_t)N0 * 4);
    size_t o_cnt  = A((size_t)N0 * 4);
    size_t o_gmax = A((size_t)BATCH * H2C * 4);
    size_t zbytes = off;
    // rest
    size_t o_src  = A((size_t)NE * 4);
    size_t o_dst  = A((size_t)NE * 4);
    size_t o_rp   = A((size_t)(N0 + 1) * 4);
    size_t o_csr  = A((size_t)NE * 4);
    size_t o_xw1  = A((size_t)N0 * H1C * 4);
    size_t o_h1   = A((size_t)N0 * H1C * 4);
    size_t o_di0  = A((size_t)N0 * 4);
    size_t o_di2  = A((size_t)N0 * 4);
    size_t o_h1w  = A((size_t)N0 * 4);
    size_t o_scr  = A((size_t)NT * 4);
    size_t o_sel  = A((size_t)NT);
    size_t o_xw2  = A((size_t)N0 * H2C * 4);
    size_t o_acc2 = A((size_t)N0 * H2C * 4);
    size_t o_flag = A(4);

    uint*  deg0 = (uint*)(ws + o_deg0);
    uint*  cnt  = (uint*)(ws + o_cnt);
    float* gmax = (float*)(ws + o_gmax);
    int*   src  = (int*)(ws + o_src);
    int*   dst  = (int*)(ws + o_dst);
    int*   rp   = (int*)(ws + o_rp);
    int*   csr  = (int*)(ws + o_csr);
    float* xw1  = (float*)(ws + o_xw1);
    float* h1   = (float*)(ws + o_h1);
    float* di0  = (float*)(ws + o_di0);
    float* di2  = (float*)(ws + o_di2);
    float* h1w  = (float*)(ws + o_h1w);
    float* scr  = (float*)(ws + o_scr);
    uchar* sel  = (uchar*)(ws + o_sel);
    float* xw2  = (float*)(ws + o_xw2);
    float* acc2 = (float*)(ws + o_acc2);
    int*   flag = (int*)(ws + o_flag);

    hipMemsetAsync(ws, 0, zbytes, stream);

    k_detect<<<1, 256, 0, stream>>>((const uint*)ei, flag);
    k_convert<<<2048, 256, 0, stream>>>(ei, flag, src, dst);
    k_deg<<<(NE + 255) / 256, 256, 0, stream>>>(dst, deg0);
    k_scan<<<1, 256, 0, stream>>>(deg0, rp);
    k_scatter<<<(NE + 255) / 256, 256, 0, stream>>>(src, dst, rp, cnt, csr);
    k_xw1<<<(N0 * H1C + 255) / 256, 256, 0, stream>>>(data, W1, xw1);
    k_dinv<<<(N0 + 255) / 256, 256, 0, stream>>>(deg0, di0);
    k_gath1<<<(N0 * 64 + 255) / 256, 256, 0, stream>>>(rp, csr, di0, xw1, b1, h1);
    k_h1w<<<(N0 + 255) / 256, 256, 0, stream>>>(h1, Wp, h1w);
    k_gscore0<<<(N0 + 255) / 256, 256, 0, stream>>>(rp, csr, di0, h1w, bp, scr);
    k_score_rest<<<(NT - N0 + 255) / 256, 256, 0, stream>>>(data, W1, b1, Wp, bp, scr);
    k_topk<<<BATCH, 1024, 0, stream>>>(scr, sel);
    k_gdinv2<<<(N0 + 255) / 256, 256, 0, stream>>>(rp, csr, sel, di2);
    k_xw2<<<(N0 * H2C + 255) / 256, 256, 0, stream>>>(h1, scr, sel, W2, xw2);
    k_gath2<<<(N0 * 64 + 255) / 256, 256, 0, stream>>>(rp, csr, sel, di2, xw2, acc2);
    k_fin2<<<(N0 + 7) / 8, 256, 0, stream>>>(acc2, xw2, di2, sel, b2, gmax);
    k_rest_pool<<<(BATCH - 1) * BPGR, 256, 0, stream>>>(data, scr, sel, W1, b1, W2, b2, gmax);
    k_final<<<1, 64, 0, stream>>>(gmax, Wf, bf, out);
}

// Round 12
// 351.671 us; speedup vs baseline: 17.6831x; 1.0975x over previous
//
#include <hip/hip_runtime.h>
#include <hip/hip_bf16.h>
#include <math.h>

#define N0   17186
#define FIN  6
#define H1C  64
#define H2C  32
#define KSEL 12031
#define BATCH 64
#define NE   500000
#define NT   (BATCH * N0)
#define SELP 17188   // sel per-graph stride, 4-aligned for packed writes

typedef unsigned int uint;
typedef unsigned char uchar;
typedef __attribute__((ext_vector_type(8))) short bf16x8;
typedef __attribute__((ext_vector_type(4))) float f32x4;

__device__ __forceinline__ uint keyOf(float f) {
    uint u = __float_as_uint(f);
    return (u & 0x80000000u) ? ~u : (u | 0x80000000u);
}

__device__ __forceinline__ short f2bf(float f) {
    union { __hip_bfloat16 b; short s; } u;
    u.b = __float2bfloat16(f);
    return u.s;
}

// ---------- edge dtype detection / normalization ----------
__global__ void k_detect(const uint* ei, int* flag64) {
    __shared__ int any;
    if (threadIdx.x == 0) any = 0;
    __syncthreads();
    for (int i = threadIdx.x; i < 1024; i += blockDim.x)
        if (ei[2 * i + 1] != 0u) any = 1;
    __syncthreads();
    if (threadIdx.x == 0) *flag64 = any ? 0 : 1;
}

__global__ void k_convert(const void* ei, const int* flag64, int* src, int* dst) {
    int f = *flag64;
    int stride = gridDim.x * blockDim.x;
    for (int i = blockIdx.x * blockDim.x + threadIdx.x; i < 2 * NE; i += stride) {
        int v = f ? (int)((const long long*)ei)[i] : ((const int*)ei)[i];
        if (i < NE) src[i] = v; else dst[i - NE] = v;
    }
}

// ---------- CSR build ----------
__global__ void k_deg(const int* dst, uint* deg) {
    int e = blockIdx.x * blockDim.x + threadIdx.x;
    if (e < NE) atomicAdd(&deg[dst[e]], 1u);
}

__global__ void k_scan(const uint* deg, int* rowptr) {
    __shared__ uint tsum[256];
    int tid = threadIdx.x;
    const int CH = (N0 + 255) / 256;  // 68
    int beg = tid * CH, end = beg + CH;
    if (end > N0) end = N0;
    uint s = 0;
    for (int i = beg; i < end; i++) s += deg[i];
    tsum[tid] = s;
    __syncthreads();
    for (int off = 1; off < 256; off <<= 1) {
        uint v = tsum[tid];
        uint a = (tid >= off) ? tsum[tid - off] : 0u;
        __syncthreads();
        tsum[tid] = v + a;
        __syncthreads();
    }
    uint run = (tid > 0) ? tsum[tid - 1] : 0u;
    for (int i = beg; i < end; i++) { rowptr[i] = (int)run; run += deg[i]; }
    if (tid == 255) rowptr[N0] = (int)run;
}

__global__ void k_scatter(const int* src, const int* dst, const int* rowptr,
                          uint* cnt, int* csr) {
    int e = blockIdx.x * blockDim.x + threadIdx.x;
    if (e < NE) {
        int d = dst[e];
        uint p = atomicAdd(&cnt[d], 1u);
        csr[rowptr[d] + (int)p] = src[e];
    }
}

// ---------- conv1 (graph 0) ----------
__global__ void k_xw1(const float* x, const float* W1, float* xw1) {
    int t = blockIdx.x * blockDim.x + threadIdx.x;
    if (t >= N0 * H1C) return;
    int i = t >> 6, h = t & 63;
    float acc = 0.f;
#pragma unroll
    for (int f = 0; f < FIN; f++) acc += x[i * FIN + f] * W1[f * H1C + h];
    xw1[t] = acc;
}

__global__ void k_dinv(const uint* deg, float* dinv) {
    int i = blockIdx.x * blockDim.x + threadIdx.x;
    if (i < N0) dinv[i] = rsqrtf(1.0f + (float)deg[i]);
}

// gather conv1 messages + finish h1 (fused fin1), 4-way unrolled
__global__ void k_gath1(const int* rowptr, const int* csr, const float* dinv,
                        const float* xw1, const float* b1, float* h1) {
    int wid = (blockIdx.x * blockDim.x + threadIdx.x) >> 6;
    int lane = threadIdx.x & 63;
    if (wid >= N0) return;
    int d = wid;
    int beg = rowptr[d], end = rowptr[d + 1];
    float a0 = 0.f, a1 = 0.f, a2 = 0.f, a3 = 0.f;
    int e = beg;
    for (; e + 4 <= end; e += 4) {
        int s0 = csr[e], s1 = csr[e + 1], s2 = csr[e + 2], s3 = csr[e + 3];
        a0 += xw1[(size_t)s0 * H1C + lane] * dinv[s0];
        a1 += xw1[(size_t)s1 * H1C + lane] * dinv[s1];
        a2 += xw1[(size_t)s2 * H1C + lane] * dinv[s2];
        a3 += xw1[(size_t)s3 * H1C + lane] * dinv[s3];
    }
    for (; e < end; e++) {
        int s = csr[e];
        a0 += xw1[(size_t)s * H1C + lane] * dinv[s];
    }
    float acc = (a0 + a1) + (a2 + a3);
    float did = dinv[d];
    float v = acc * did + xw1[(size_t)d * H1C + lane] * did * did + b1[lane];
    h1[(size_t)d * H1C + lane] = fmaxf(v, 0.f);
}

// ---------- pooling score ----------
__global__ void k_h1w(const float* h1, const float* Wp, float* h1w) {
    int i = blockIdx.x * blockDim.x + threadIdx.x;
    if (i >= N0) return;
    const float* row = h1 + (size_t)i * H1C;
    float acc = 0.f;
#pragma unroll
    for (int h = 0; h < H1C; h++) acc += row[h] * Wp[h];
    h1w[i] = acc;
}

// graph-0 score: gather + self-loop (fused smsg+score0)
__global__ void k_gscore0(const int* rowptr, const int* csr, const float* dinv,
                          const float* h1w, const float* bp, float* score) {
    int d = blockIdx.x * blockDim.x + threadIdx.x;
    if (d >= N0) return;
    float acc = 0.f;
    int beg = rowptr[d], end = rowptr[d + 1];
    for (int e = beg; e < end; e++) {
        int s = csr[e];
        acc += h1w[s] * dinv[s];
    }
    float did = dinv[d];
    score[d] = acc * did + h1w[d] * did * did + bp[0];
}

// graphs 1..63: score = relu(x@W1+b1) . Wp + bp
__global__ void k_score_rest(const float* __restrict__ x, const float* __restrict__ W1,
                             const float* __restrict__ b1, const float* __restrict__ Wp,
                             const float* __restrict__ bp, float* score) {
    __shared__ __align__(16) float sW[H1C * 8];
    int tid = threadIdx.x;
    if (tid < H1C) {
#pragma unroll
        for (int f = 0; f < FIN; f++) sW[tid * 8 + f] = W1[f * H1C + tid];
        sW[tid * 8 + 6] = b1[tid];
        sW[tid * 8 + 7] = Wp[tid];
    }
    __syncthreads();
    int idx = blockIdx.x * blockDim.x + tid;
    int n = N0 + idx;
    if (n >= NT) return;
    const float2* xv = reinterpret_cast<const float2*>(x) + (size_t)n * 3;
    float2 x01 = xv[0], x23 = xv[1], x45 = xv[2];
    float sc = bp[0];
#pragma unroll
    for (int h = 0; h < H1C; h++) {
        float4 wa = *reinterpret_cast<const float4*>(&sW[h * 8]);
        float4 wb = *reinterpret_cast<const float4*>(&sW[h * 8 + 4]);
        float a = wb.z;                       // b1[h]
        a += x01.x * wa.x; a += x01.y * wa.y;
        a += x23.x * wa.z; a += x23.y * wa.w;
        a += x45.x * wb.x; a += x45.y * wb.y;
        sc += fmaxf(a, 0.f) * wb.w;           // Wp[h]
    }
    score[n] = sc;
}

// ---------- per-graph top-K selection (radix select, v3) ----------
// R11: 57us, VALUBusy 4% -> serial digit scan + barrier-heavy tail + L2
// re-reads. v3: keys register-resident (load once, 5x float4/thread),
// parallel shfl suffix-scan digit selection (2 barriers), 5-chunk tail
// with wave shfl_up prefix + packed uchar4 sel writes. Same semantics.
__global__ __launch_bounds__(1024)
void k_topk(const float* __restrict__ score, uchar* __restrict__ sel) {
    int g = blockIdx.x;
    const float* sc = score + (size_t)g * N0;
    uchar* sl = sel + (size_t)g * SELP;
    __shared__ uint hist[16][256];
    __shared__ uint sbuf[256];
    __shared__ uint wpart[4];
    __shared__ uint wtot[16];
    __shared__ uint shPrefix, shWant;
    int tid = threadIdx.x;
    int wave = tid >> 6, lane = tid & 63;

    // register-resident keys: 5 chunks x 4 elems (static indexing)
    uint key[5][4];
#pragma unroll
    for (int c = 0; c < 5; c++) {
        int base = c * 4096 + tid * 4;
        if (base + 3 < N0) {
            float4 v = *reinterpret_cast<const float4*>(sc + base);
            key[c][0] = keyOf(v.x); key[c][1] = keyOf(v.y);
            key[c][2] = keyOf(v.z); key[c][3] = keyOf(v.w);
        } else {
#pragma unroll
            for (int j = 0; j < 4; j++)
                key[c][j] = (base + j < N0) ? keyOf(sc[base + j]) : 0u;
        }
    }

    uint prefix = 0, want = KSEL;
#pragma unroll 1
    for (int pass = 0; pass < 4; pass++) {
        int shift = 24 - 8 * pass;
        for (int i = tid; i < 16 * 256; i += 1024) ((uint*)hist)[i] = 0;
        __syncthreads();
        uint* hw = hist[wave];
#pragma unroll
        for (int c = 0; c < 5; c++) {
            int base = c * 4096 + tid * 4;
#pragma unroll
            for (int j = 0; j < 4; j++) {
                uint k = key[c][j];
                bool valid = (base + j) < N0;
                bool active = valid && ((pass == 0) || ((k >> (shift + 8)) == prefix));
                if (active) atomicAdd(&hw[(k >> shift) & 255], 1u);
            }
        }
        __syncthreads();
        // merge 16 per-wave hists, then suffix-scan over 256 bins
        uint v = 0;
        if (tid < 256) {
#pragma unroll
            for (int w = 0; w < 16; w++) v += hist[w][tid];
        }
#pragma unroll
        for (int off = 1; off < 64; off <<= 1) {
            uint u = __shfl_down(v, off, 64);
            if (lane + off < 64) v += u;
        }
        if (tid < 256 && lane == 0) wpart[wave] = v;
        __syncthreads();
        if (tid < 256) {
#pragma unroll
            for (int w = 0; w < 4; w++) if (w > wave) v += wpart[w];
            sbuf[tid] = v;                    // suffix sum: bins >= tid
        }
        __syncthreads();
        if (tid < 256) {
            uint s = sbuf[tid];
            uint snext = (tid == 255) ? 0u : sbuf[tid + 1];
            if (s >= want && snext < want) {
                shPrefix = (prefix << 8) | (uint)tid;
                shWant = want - snext;
            }
        }
        __syncthreads();
        prefix = shPrefix; want = shWant;
        __syncthreads();
    }

    uint T = prefix, needEq = want;
    uint runningEq = 0;
#pragma unroll 1
    for (int c = 0; c < 5; c++) {
        int base = c * 4096 + tid * 4;
        uint e0 = ((base + 0) < N0 && key[c][0] == T) ? 1u : 0u;
        uint e1 = ((base + 1) < N0 && key[c][1] == T) ? 1u : 0u;
        uint e2 = ((base + 2) < N0 && key[c][2] == T) ? 1u : 0u;
        uint e3 = ((base + 3) < N0 && key[c][3] == T) ? 1u : 0u;
        uint cnt = e0 + e1 + e2 + e3;
        uint pref = cnt;
#pragma unroll
        for (int off = 1; off < 64; off <<= 1) {
            uint u = __shfl_up(pref, off, 64);
            if (lane >= off) pref += u;
        }
        if (lane == 63) wtot[wave] = pref;
        __syncthreads();
        uint before = 0, total = 0;
#pragma unroll
        for (int w = 0; w < 16; w++) {
            uint t = wtot[w];
            if (w < wave) before += t;
            total += t;
        }
        uint offs = runningEq + before + (pref - cnt);
        uint local = 0;
        uchar sv[4];
        {
            uint k = key[c][0];
            uchar s = 0;
            if ((base + 0) < N0) {
                if (k > T) s = 1;
                else if (e0 && (offs + local) < needEq) s = 1;
            }
            local += e0; sv[0] = s;
        }
        {
            uint k = key[c][1];
            uchar s = 0;
            if ((base + 1) < N0) {
                if (k > T) s = 1;
                else if (e1 && (offs + local) < needEq) s = 1;
            }
            local += e1; sv[1] = s;
        }
        {
            uint k = key[c][2];
            uchar s = 0;
            if ((base + 2) < N0) {
                if (k > T) s = 1;
                else if (e2 && (offs + local) < needEq) s = 1;
            }
            local += e2; sv[2] = s;
        }
        {
            uint k = key[c][3];
            uchar s = 0;
            if ((base + 3) < N0) {
                if (k > T) s = 1;
                else if (e3 && (offs + local) < needEq) s = 1;
            }
            local += e3; sv[3] = s;
        }
        if (base + 3 < N0) {
            uint packed = (uint)sv[0] | ((uint)sv[1] << 8) | ((uint)sv[2] << 16) | ((uint)sv[3] << 24);
            *reinterpret_cast<uint*>(sl + base) = packed;
        } else {
#pragma unroll
            for (int j = 0; j < 4; j++) if (base + j < N0) sl[base + j] = sv[j];
        }
        runningEq += total;
        __syncthreads();
    }
}

// ---------- conv2 (graph 0, selection-filtered) ----------
__global__ void k_gdinv2(const int* rowptr, const int* csr, const uchar* sel,
                         float* dinv2) {
    int d = blockIdx.x * blockDim.x + threadIdx.x;
    if (d >= N0) return;
    float r = 0.f;
    if (sel[d]) {
        int c = 0;
        int beg = rowptr[d], end = rowptr[d + 1];
        for (int e = beg; e < end; e++) c += sel[csr[e]];
        r = rsqrtf(1.f + (float)c);
    }
    dinv2[d] = r;
}

__global__ void k_xw2(const float* h1, const float* score, const uchar* sel,
                      const float* W2, float* xw2) {
    int gt = blockIdx.x * blockDim.x + threadIdx.x;
    int i = gt >> 5, c = gt & 31;
    if (i >= N0) return;
    if (!sel[i]) return;
    float t = tanhf(score[i]);
    const float* row = h1 + (size_t)i * H1C;
    float acc = 0.f;
#pragma unroll
    for (int h = 0; h < H1C; h++) acc += row[h] * W2[h * H2C + c];
    xw2[i * H2C + c] = acc * t;
}

__global__ void k_gath2(const int* rowptr, const int* csr, const uchar* sel,
                        const float* dinv2, const float* xw2, float* acc2) {
    int wid = (blockIdx.x * blockDim.x + threadIdx.x) >> 6;
    int lane = threadIdx.x & 63;
    if (wid >= N0) return;
    int d = wid;
    if (!sel[d]) return;
    int c = lane & 31;
    int beg = rowptr[d], end = rowptr[d + 1];
    float a0 = 0.f, a1 = 0.f;
    int e = beg + (lane >> 5);
    for (; e + 2 < end; e += 4) {   // this half-wave handles e, e+2
        int s0 = csr[e], s1 = csr[e + 2];
        a0 += xw2[(size_t)s0 * H2C + c] * dinv2[s0];
        a1 += xw2[(size_t)s1 * H2C + c] * dinv2[s1];
    }
    if (e < end) {
        int s = csr[e];
        a0 += xw2[(size_t)s * H2C + c] * dinv2[s];
    }
    float acc = a0 + a1;
    acc += __shfl_xor(acc, 32, 64);
    if (lane < 32) acc2[(size_t)d * H2C + c] = acc * dinv2[d];
}

__global__ void k_fin2(const float* acc2, const float* xw2, const float* dinv2,
                       const uchar* sel, const float* b2, float* gmax) {
    __shared__ float m[32];
    int tid = threadIdx.x;
    if (tid < 32) m[tid] = 0.f;
    __syncthreads();
    int i = blockIdx.x * 8 + (tid >> 5);
    int c = tid & 31;
    float v = 0.f;
    if (i < N0 && sel[i]) {
        float di = dinv2[i];
        v = fmaxf(acc2[(size_t)i * H2C + c] + xw2[(size_t)i * H2C + c] * di * di + b2[c], 0.f);
    }
    atomicMax((int*)&m[c], __float_as_int(v));
    __syncthreads();
    if (tid < 32) atomicMax((int*)&gmax[tid], __float_as_int(m[tid]));
}

// ---------- graphs 1..63: h2 + max pool, BOTH layers via MFMA (v4) ----------
#define BPGR 68
__global__ __launch_bounds__(256, 2)
void k_rest_pool(const float* __restrict__ x, const float* __restrict__ score,
                 const uchar* __restrict__ sel,
                 const float* __restrict__ W1, const float* __restrict__ b1,
                 const float* __restrict__ W2, const float* __restrict__ b2,
                 float* gmax) {
    __shared__ __align__(16) short sW2T[H2C * 72];
    __shared__ __align__(16) short h1T[4][16 * 72];
    __shared__ float ltl[256];
    __shared__ float lmk[256];
    __shared__ float m[H2C];
    int tid = threadIdx.x;
    if (tid < H2C) m[tid] = 0.f;
    {   // W2^T bf16 staging: sW2T[c][k], row stride 72 shorts (144B)
        int c = tid >> 3, k0 = (tid & 7) * 8;
#pragma unroll
        for (int k = 0; k < 8; k++)
            sW2T[c * 72 + k0 + k] = f2bf(W2[(k0 + k) * H2C + c]);
    }
    int lane = tid & 63;
    int wv = tid >> 6;
    int g = blockIdx.x / BPGR + 1;
    int wslot = (blockIdx.x % BPGR) * 4 + wv;
    int nbase = wslot * 64;
    {   // per-node tanh / mask for this wave's 64 nodes
        int li = nbase + lane;
        bool inb = li < N0;
        int n = g * N0 + (inb ? li : 0);
        bool valid = inb && sel[(size_t)g * SELP + (inb ? li : 0)];
        ltl[tid] = valid ? tanhf(score[n]) : 0.f;
        lmk[tid] = valid ? 1.f : 0.f;
    }
    __syncthreads();

    int col = lane & 15;
    int q = lane >> 4;
    int kb8 = q * 8;
    int wbase = wv * 64;
    short* hrow = &h1T[wv][0];

    // Layer-1 B fragments: W1~[k][h], rows 0-5 = W1, row 6 = b1, rows 7..31 = 0.
    bf16x8 B1a = {0, 0, 0, 0, 0, 0, 0, 0};
    bf16x8 B1b = {0, 0, 0, 0, 0, 0, 0, 0};
    bf16x8 B1c = {0, 0, 0, 0, 0, 0, 0, 0};
    bf16x8 B1d = {0, 0, 0, 0, 0, 0, 0, 0};
    if (q == 0) {
#pragma unroll
        for (int j = 0; j < 6; j++) {
            B1a[j] = f2bf(W1[j * H1C + col]);
            B1b[j] = f2bf(W1[j * H1C + 16 + col]);
            B1c[j] = f2bf(W1[j * H1C + 32 + col]);
            B1d[j] = f2bf(W1[j * H1C + 48 + col]);
        }
        B1a[6] = f2bf(b1[col]);
        B1b[6] = f2bf(b1[16 + col]);
        B1c[6] = f2bf(b1[32 + col]);
        B1d[6] = f2bf(b1[48 + col]);
    }
    float b2c0 = b2[col], b2c1 = b2[col + 16];

    float rm0 = 0.f, rm1 = 0.f;
#pragma unroll 1
    for (int grp = 0; grp < 4; grp++) {
        bf16x8 A0 = {0, 0, 0, 0, 0, 0, 0, 0};
        if (q == 0) {
            float tlc = ltl[wbase + grp * 16 + col];
            if (tlc != 0.f) {
                int n = g * N0 + nbase + grp * 16 + col;
                const float2* xv = reinterpret_cast<const float2*>(x) + (size_t)n * 3;
                float2 x01 = xv[0], x23 = xv[1], x45 = xv[2];
                A0[0] = f2bf(x01.x); A0[1] = f2bf(x01.y);
                A0[2] = f2bf(x23.x); A0[3] = f2bf(x23.y);
                A0[4] = f2bf(x45.x); A0[5] = f2bf(x45.y);
            }
            A0[6] = f2bf(1.0f);
        }
        float tn0 = ltl[wbase + grp * 16 + q * 4 + 0];
        float tn1 = ltl[wbase + grp * 16 + q * 4 + 1];
        float tn2 = ltl[wbase + grp * 16 + q * 4 + 2];
        float tn3 = ltl[wbase + grp * 16 + q * 4 + 3];
        {
            f32x4 hz = {0.f, 0.f, 0.f, 0.f};
            f32x4 h = __builtin_amdgcn_mfma_f32_16x16x32_bf16(A0, B1a, hz, 0, 0, 0);
            hrow[(q * 4 + 0) * 72 + col]      = f2bf(tn0 * fmaxf(h[0], 0.f));
            hrow[(q * 4 + 1) * 72 + col]      = f2bf(tn1 * fmaxf(h[1], 0.f));
            hrow[(q * 4 + 2) * 72 + col]      = f2bf(tn2 * fmaxf(h[2], 0.f));
            hrow[(q * 4 + 3) * 72 + col]      = f2bf(tn3 * fmaxf(h[3], 0.f));
            h = __builtin_amdgcn_mfma_f32_16x16x32_bf16(A0, B1b, hz, 0, 0, 0);
            hrow[(q * 4 + 0) * 72 + 16 + col] = f2bf(tn0 * fmaxf(h[0], 0.f));
            hrow[(q * 4 + 1) * 72 + 16 + col] = f2bf(tn1 * fmaxf(h[1], 0.f));
            hrow[(q * 4 + 2) * 72 + 16 + col] = f2bf(tn2 * fmaxf(h[2], 0.f));
            hrow[(q * 4 + 3) * 72 + 16 + col] = f2bf(tn3 * fmaxf(h[3], 0.f));
            h = __builtin_amdgcn_mfma_f32_16x16x32_bf16(A0, B1c, hz, 0, 0, 0);
            hrow[(q * 4 + 0) * 72 + 32 + col] = f2bf(tn0 * fmaxf(h[0], 0.f));
            hrow[(q * 4 + 1) * 72 + 32 + col] = f2bf(tn1 * fmaxf(h[1], 0.f));
            hrow[(q * 4 + 2) * 72 + 32 + col] = f2bf(tn2 * fmaxf(h[2], 0.f));
            hrow[(q * 4 + 3) * 72 + 32 + col] = f2bf(tn3 * fmaxf(h[3], 0.f));
            h = __builtin_amdgcn_mfma_f32_16x16x32_bf16(A0, B1d, hz, 0, 0, 0);
            hrow[(q * 4 + 0) * 72 + 48 + col] = f2bf(tn0 * fmaxf(h[0], 0.f));
            hrow[(q * 4 + 1) * 72 + 48 + col] = f2bf(tn1 * fmaxf(h[1], 0.f));
            hrow[(q * 4 + 2) * 72 + 48 + col] = f2bf(tn2 * fmaxf(h[2], 0.f));
            hrow[(q * 4 + 3) * 72 + 48 + col] = f2bf(tn3 * fmaxf(h[3], 0.f));
        }
        bf16x8 A2_0 = *reinterpret_cast<const bf16x8*>(&hrow[col * 72 + kb8]);
        bf16x8 A2_1 = *reinterpret_cast<const bf16x8*>(&hrow[col * 72 + 32 + kb8]);
        f32x4 acc0 = {0.f, 0.f, 0.f, 0.f};
        f32x4 acc1 = {0.f, 0.f, 0.f, 0.f};
        acc0 = __builtin_amdgcn_mfma_f32_16x16x32_bf16(
            A2_0, *reinterpret_cast<const bf16x8*>(&sW2T[col * 72 + kb8]), acc0, 0, 0, 0);
        acc0 = __builtin_amdgcn_mfma_f32_16x16x32_bf16(
            A2_1, *reinterpret_cast<const bf16x8*>(&sW2T[col * 72 + 32 + kb8]), acc0, 0, 0, 0);
        acc1 = __builtin_amdgcn_mfma_f32_16x16x32_bf16(
            A2_0, *reinterpret_cast<const bf16x8*>(&sW2T[(col + 16) * 72 + kb8]), acc1, 0, 0, 0);
        acc1 = __builtin_amdgcn_mfma_f32_16x16x32_bf16(
            A2_1, *reinterpret_cast<const bf16x8*>(&sW2T[(col + 16) * 72 + 32 + kb8]), acc1, 0, 0, 0);
        float mk0 = lmk[wbase + grp * 16 + q * 4 + 0];
        float mk1 = lmk[wbase + grp * 16 + q * 4 + 1];
        float mk2 = lmk[wbase + grp * 16 + q * 4 + 2];
        float mk3 = lmk[wbase + grp * 16 + q * 4 + 3];
        rm0 = fmaxf(rm0, mk0 * fmaxf(acc0[0] + b2c0, 0.f));
        rm0 = fmaxf(rm0, mk1 * fmaxf(acc0[1] + b2c0, 0.f));
        rm0 = fmaxf(rm0, mk2 * fmaxf(acc0[2] + b2c0, 0.f));
        rm0 = fmaxf(rm0, mk3 * fmaxf(acc0[3] + b2c0, 0.f));
        rm1 = fmaxf(rm1, mk0 * fmaxf(acc1[0] + b2c1, 0.f));
        rm1 = fmaxf(rm1, mk1 * fmaxf(acc1[1] + b2c1, 0.f));
        rm1 = fmaxf(rm1, mk2 * fmaxf(acc1[2] + b2c1, 0.f));
        rm1 = fmaxf(rm1, mk3 * fmaxf(acc1[3] + b2c1, 0.f));
    }
    rm0 = fmaxf(rm0, __shfl_xor(rm0, 16, 64));
    rm0 = fmaxf(rm0, __shfl_xor(rm0, 32, 64));
    rm1 = fmaxf(rm1, __shfl_xor(rm1, 16, 64));
    rm1 = fmaxf(rm1, __shfl_xor(rm1, 32, 64));
    if (lane < 16) {
        atomicMax((int*)&m[col], __float_as_int(rm0));
        atomicMax((int*)&m[col + 16], __float_as_int(rm1));
    }
    __syncthreads();
    if (tid < H2C) atomicMax((int*)&gmax[g * H2C + tid], __float_as_int(m[tid]));
}

// ---------- readout ----------
__global__ void k_final(const float* gmax, const float* Wf, const float* bf, float* out) {
    int g = threadIdx.x;
    if (g < BATCH) {
        float acc = bf[0];
        for (int c = 0; c < H2C; c++) acc += gmax[g * H2C + c] * Wf[c];
        out[g] = 1.f / (1.f + expf(-acc));
    }
}

extern "C" void kernel_launch(void* const* d_in, const int* in_sizes, int n_in,
                              void* d_out, int out_size, void* d_ws, size_t ws_size,
                              hipStream_t stream) {
    const float* data = (const float*)d_in[0];
    const void*  ei   = d_in[1];
    const float* W1   = (const float*)d_in[2];
    const float* b1   = (const float*)d_in[3];
    const float* Wp   = (const float*)d_in[4];
    const float* bp   = (const float*)d_in[5];
    const float* W2   = (const float*)d_in[6];
    const float* b2   = (const float*)d_in[7];
    const float* Wf   = (const float*)d_in[8];
    const float* bf   = (const float*)d_in[9];
    float* out = (float*)d_out;

    char* ws = (char*)d_ws;
    size_t off = 0;
    auto A = [&](size_t bytes) -> size_t {
        size_t o = off; off += (bytes + 511) & ~(size_t)511; return o;
    };
    // zero-initialized region (single memset)
    size_t o_deg0 = A((size_t)N0 * 4);
    size_t o_cnt  = A((size_t)N0 * 4);
    size_t o_gmax = A((size_t)BATCH * H2C * 4);
    size_t zbytes = off;
    // rest
    size_t o_src  = A((size_t)NE * 4);
    size_t o_dst  = A((size_t)NE * 4);
    size_t o_rp   = A((size_t)(N0 + 1) * 4);
    size_t o_csr  = A((size_t)NE * 4);
    size_t o_xw1  = A((size_t)N0 * H1C * 4);
    size_t o_h1   = A((size_t)N0 * H1C * 4);
    size_t o_di0  = A((size_t)N0 * 4);
    size_t o_di2  = A((size_t)N0 * 4);
    size_t o_h1w  = A((size_t)N0 * 4);
    size_t o_scr  = A((size_t)NT * 4);
    size_t o_sel  = A((size_t)BATCH * SELP);
    size_t o_xw2  = A((size_t)N0 * H2C * 4);
    size_t o_acc2 = A((size_t)N0 * H2C * 4);
    size_t o_flag = A(4);

    uint*  deg0 = (uint*)(ws + o_deg0);
    uint*  cnt  = (uint*)(ws + o_cnt);
    float* gmax = (float*)(ws + o_gmax);
    int*   src  = (int*)(ws + o_src);
    int*   dst  = (int*)(ws + o_dst);
    int*   rp   = (int*)(ws + o_rp);
    int*   csr  = (int*)(ws + o_csr);
    float* xw1  = (float*)(ws + o_xw1);
    float* h1   = (float*)(ws + o_h1);
    float* di0  = (float*)(ws + o_di0);
    float* di2  = (float*)(ws + o_di2);
    float* h1w  = (float*)(ws + o_h1w);
    float* scr  = (float*)(ws + o_scr);
    uchar* sel  = (uchar*)(ws + o_sel);
    float* xw2  = (float*)(ws + o_xw2);
    float* acc2 = (float*)(ws + o_acc2);
    int*   flag = (int*)(ws + o_flag);

    hipMemsetAsync(ws, 0, zbytes, stream);

    k_detect<<<1, 256, 0, stream>>>((const uint*)ei, flag);
    k_convert<<<2048, 256, 0, stream>>>(ei, flag, src, dst);
    k_deg<<<(NE + 255) / 256, 256, 0, stream>>>(dst, deg0);
    k_scan<<<1, 256, 0, stream>>>(deg0, rp);
    k_scatter<<<(NE + 255) / 256, 256, 0, stream>>>(src, dst, rp, cnt, csr);
    k_xw1<<<(N0 * H1C + 255) / 256, 256, 0, stream>>>(data, W1, xw1);
    k_dinv<<<(N0 + 255) / 256, 256, 0, stream>>>(deg0, di0);
    k_gath1<<<(N0 * 64 + 255) / 256, 256, 0, stream>>>(rp, csr, di0, xw1, b1, h1);
    k_h1w<<<(N0 + 255) / 256, 256, 0, stream>>>(h1, Wp, h1w);
    k_gscore0<<<(N0 + 255) / 256, 256, 0, stream>>>(rp, csr, di0, h1w, bp, scr);
    k_score_rest<<<(NT - N0 + 255) / 256, 256, 0, stream>>>(data, W1, b1, Wp, bp, scr);
    k_topk<<<BATCH, 1024, 0, stream>>>(scr, sel);
    k_gdinv2<<<(N0 + 255) / 256, 256, 0, stream>>>(rp, csr, sel, di2);
    k_xw2<<<(N0 * H2C + 255) / 256, 256, 0, stream>>>(h1, scr, sel, W2, xw2);
    k_gath2<<<(N0 * 64 + 255) / 256, 256, 0, stream>>>(rp, csr, sel, di2, xw2, acc2);
    k_fin2<<<(N0 + 7) / 8, 256, 0, stream>>>(acc2, xw2, di2, sel, b2, gmax);
    k_rest_pool<<<(BATCH - 1) * BPGR, 256, 0, stream>>>(data, scr, sel, W1, b1, W2, b2, gmax);
    k_final<<<1, 64, 0, stream>>>(gmax, Wf, bf, out);
}

// Round 13
// 343.719 us; speedup vs baseline: 18.0922x; 1.0231x over previous
//
#include <hip/hip_runtime.h>
#include <hip/hip_bf16.h>
#include <math.h>

#define N0   17186
#define FIN  6
#define H1C  64
#define H2C  32
#define KSEL 12031
#define BATCH 64
#define NE   500000
#define NT   (BATCH * N0)
#define SELP 17188   // sel per-graph stride, 4-aligned for packed writes

typedef unsigned int uint;
typedef unsigned char uchar;
typedef __attribute__((ext_vector_type(8))) short bf16x8;
typedef __attribute__((ext_vector_type(4))) float f32x4;

__device__ __forceinline__ uint keyOf(float f) {
    uint u = __float_as_uint(f);
    return (u & 0x80000000u) ? ~u : (u | 0x80000000u);
}

__device__ __forceinline__ short f2bf(float f) {
    union { __hip_bfloat16 b; short s; } u;
    u.b = __float2bfloat16(f);
    return u.s;
}

// ---------- edge normalization (inline dtype detect) + dst-degree ----------
// Per-block detection: sample high words of first 1024 entries; int64 iff all
// zero (node ids are random in [0,17186) -> P(false positive) ~ 0). Same
// deterministic result in every block. Degree counted while writing dst.
__global__ void k_convert(const void* ei, int* src, int* dst, uint* deg) {
    __shared__ int any;
    int tid = threadIdx.x;
    if (tid == 0) any = 0;
    __syncthreads();
    const uint* w = (const uint*)ei;
    for (int i = tid; i < 1024; i += 256)
        if (w[2 * i + 1] != 0u) any = 1;
    __syncthreads();
    int f64 = (any == 0);
    int stride = gridDim.x * blockDim.x;
    for (int i = blockIdx.x * blockDim.x + tid; i < 2 * NE; i += stride) {
        int v = f64 ? (int)((const long long*)ei)[i] : ((const int*)ei)[i];
        if (i < NE) src[i] = v;
        else { dst[i - NE] = v; atomicAdd(&deg[v], 1u); }
    }
}

// ---------- CSR build: scan (+ fused dinv) ----------
__global__ void k_scan(const uint* deg, int* rowptr, float* dinv) {
    __shared__ uint tsum[256];
    int tid = threadIdx.x;
    const int CH = (N0 + 255) / 256;  // 68
    int beg = tid * CH, end = beg + CH;
    if (end > N0) end = N0;
    uint s = 0;
    for (int i = beg; i < end; i++) s += deg[i];
    tsum[tid] = s;
    __syncthreads();
    for (int off = 1; off < 256; off <<= 1) {
        uint v = tsum[tid];
        uint a = (tid >= off) ? tsum[tid - off] : 0u;
        __syncthreads();
        tsum[tid] = v + a;
        __syncthreads();
    }
    uint run = (tid > 0) ? tsum[tid - 1] : 0u;
    for (int i = beg; i < end; i++) {
        uint dg = deg[i];
        rowptr[i] = (int)run;
        dinv[i] = rsqrtf(1.0f + (float)dg);
        run += dg;
    }
    if (tid == 255) rowptr[N0] = (int)run;
}

__global__ void k_scatter(const int* src, const int* dst, const int* rowptr,
                          uint* cnt, int* csr) {
    int e = blockIdx.x * blockDim.x + threadIdx.x;
    if (e < NE) {
        int d = dst[e];
        uint p = atomicAdd(&cnt[d], 1u);
        csr[rowptr[d] + (int)p] = src[e];
    }
}

// ---------- fat kernel: xw1 (graph 0) + score for graphs 1..63 ----------
#define XW1_BLOCKS ((N0 * H1C + 255) / 256)   // 4297
__global__ void k_feat(const float* __restrict__ x, const float* __restrict__ W1,
                       const float* __restrict__ b1, const float* __restrict__ Wp,
                       const float* __restrict__ bp,
                       float* xw1, float* score) {
    __shared__ __align__(16) float sW[H1C * 8];
    int tid = threadIdx.x;
    int b = blockIdx.x;
    if (b < XW1_BLOCKS) {
        int t = b * 256 + tid;
        if (t >= N0 * H1C) return;
        int i = t >> 6, h = t & 63;
        float acc = 0.f;
#pragma unroll
        for (int f = 0; f < FIN; f++) acc += x[i * FIN + f] * W1[f * H1C + h];
        xw1[t] = acc;
    } else {
        if (tid < H1C) {
#pragma unroll
            for (int f = 0; f < FIN; f++) sW[tid * 8 + f] = W1[f * H1C + tid];
            sW[tid * 8 + 6] = b1[tid];
            sW[tid * 8 + 7] = Wp[tid];
        }
        __syncthreads();
        int idx = (b - XW1_BLOCKS) * 256 + tid;
        int n = N0 + idx;
        if (n >= NT) return;
        const float2* xv = reinterpret_cast<const float2*>(x) + (size_t)n * 3;
        float2 x01 = xv[0], x23 = xv[1], x45 = xv[2];
        float sc = bp[0];
#pragma unroll
        for (int h = 0; h < H1C; h++) {
            float4 wa = *reinterpret_cast<const float4*>(&sW[h * 8]);
            float4 wb = *reinterpret_cast<const float4*>(&sW[h * 8 + 4]);
            float a = wb.z;                       // b1[h]
            a += x01.x * wa.x; a += x01.y * wa.y;
            a += x23.x * wa.z; a += x23.y * wa.w;
            a += x45.x * wb.x; a += x45.y * wb.y;
            sc += fmaxf(a, 0.f) * wb.w;           // Wp[h]
        }
        score[n] = sc;
    }
}

// gather conv1 + finish h1 + fused h1w/hp (wave shfl reduce over channels)
__global__ void k_gath1(const int* rowptr, const int* csr, const float* dinv,
                        const float* xw1, const float* b1, const float* Wp,
                        float* h1, float* h1w, float* hp) {
    int wid = (blockIdx.x * blockDim.x + threadIdx.x) >> 6;
    int lane = threadIdx.x & 63;
    if (wid >= N0) return;
    int d = wid;
    int beg = rowptr[d], end = rowptr[d + 1];
    float a0 = 0.f, a1 = 0.f, a2 = 0.f, a3 = 0.f;
    int e = beg;
    for (; e + 4 <= end; e += 4) {
        int s0 = csr[e], s1 = csr[e + 1], s2 = csr[e + 2], s3 = csr[e + 3];
        a0 += xw1[(size_t)s0 * H1C + lane] * dinv[s0];
        a1 += xw1[(size_t)s1 * H1C + lane] * dinv[s1];
        a2 += xw1[(size_t)s2 * H1C + lane] * dinv[s2];
        a3 += xw1[(size_t)s3 * H1C + lane] * dinv[s3];
    }
    for (; e < end; e++) {
        int s = csr[e];
        a0 += xw1[(size_t)s * H1C + lane] * dinv[s];
    }
    float acc = (a0 + a1) + (a2 + a3);
    float did = dinv[d];
    float v = acc * did + xw1[(size_t)d * H1C + lane] * did * did + b1[lane];
    v = fmaxf(v, 0.f);
    h1[(size_t)d * H1C + lane] = v;
    float wv = v * Wp[lane];
#pragma unroll
    for (int o = 32; o > 0; o >>= 1) wv += __shfl_xor(wv, o, 64);
    if (lane == 0) { h1w[d] = wv; hp[d] = wv * did; }
}

// graph-0 score: gather hp (one float/edge) + self-loop
__global__ void k_gscore0(const int* rowptr, const int* csr, const float* dinv,
                          const float* hp, const float* h1w, const float* bp,
                          float* score) {
    int d = blockIdx.x * blockDim.x + threadIdx.x;
    if (d >= N0) return;
    float acc = 0.f;
    int beg = rowptr[d], end = rowptr[d + 1];
    for (int e = beg; e < end; e++) acc += hp[csr[e]];
    float did = dinv[d];
    score[d] = acc * did + h1w[d] * did * did + bp[0];
}

// ---------- per-graph top-K selection (radix select, v3) ----------
__global__ __launch_bounds__(1024)
void k_topk(const float* __restrict__ score, uchar* __restrict__ sel) {
    int g = blockIdx.x;
    const float* sc = score + (size_t)g * N0;
    uchar* sl = sel + (size_t)g * SELP;
    __shared__ uint hist[16][256];
    __shared__ uint sbuf[256];
    __shared__ uint wpart[4];
    __shared__ uint wtot[16];
    __shared__ uint shPrefix, shWant;
    int tid = threadIdx.x;
    int wave = tid >> 6, lane = tid & 63;

    uint key[5][4];
#pragma unroll
    for (int c = 0; c < 5; c++) {
        int base = c * 4096 + tid * 4;
        if (base + 3 < N0) {
            float4 v = *reinterpret_cast<const float4*>(sc + base);
            key[c][0] = keyOf(v.x); key[c][1] = keyOf(v.y);
            key[c][2] = keyOf(v.z); key[c][3] = keyOf(v.w);
        } else {
#pragma unroll
            for (int j = 0; j < 4; j++)
                key[c][j] = (base + j < N0) ? keyOf(sc[base + j]) : 0u;
        }
    }

    uint prefix = 0, want = KSEL;
#pragma unroll 1
    for (int pass = 0; pass < 4; pass++) {
        int shift = 24 - 8 * pass;
        for (int i = tid; i < 16 * 256; i += 1024) ((uint*)hist)[i] = 0;
        __syncthreads();
        uint* hw = hist[wave];
#pragma unroll
        for (int c = 0; c < 5; c++) {
            int base = c * 4096 + tid * 4;
#pragma unroll
            for (int j = 0; j < 4; j++) {
                uint k = key[c][j];
                bool valid = (base + j) < N0;
                bool active = valid && ((pass == 0) || ((k >> (shift + 8)) == prefix));
                if (active) atomicAdd(&hw[(k >> shift) & 255], 1u);
            }
        }
        __syncthreads();
        uint v = 0;
        if (tid < 256) {
#pragma unroll
            for (int w = 0; w < 16; w++) v += hist[w][tid];
        }
#pragma unroll
        for (int off = 1; off < 64; off <<= 1) {
            uint u = __shfl_down(v, off, 64);
            if (lane + off < 64) v += u;
        }
        if (tid < 256 && lane == 0) wpart[wave] = v;
        __syncthreads();
        if (tid < 256) {
#pragma unroll
            for (int w = 0; w < 4; w++) if (w > wave) v += wpart[w];
            sbuf[tid] = v;                    // suffix sum: bins >= tid
        }
        __syncthreads();
        if (tid < 256) {
            uint s = sbuf[tid];
            uint snext = (tid == 255) ? 0u : sbuf[tid + 1];
            if (s >= want && snext < want) {
                shPrefix = (prefix << 8) | (uint)tid;
                shWant = want - snext;
            }
        }
        __syncthreads();
        prefix = shPrefix; want = shWant;
        __syncthreads();
    }

    uint T = prefix, needEq = want;
    uint runningEq = 0;
#pragma unroll 1
    for (int c = 0; c < 5; c++) {
        int base = c * 4096 + tid * 4;
        uint e0 = ((base + 0) < N0 && key[c][0] == T) ? 1u : 0u;
        uint e1 = ((base + 1) < N0 && key[c][1] == T) ? 1u : 0u;
        uint e2 = ((base + 2) < N0 && key[c][2] == T) ? 1u : 0u;
        uint e3 = ((base + 3) < N0 && key[c][3] == T) ? 1u : 0u;
        uint cnt = e0 + e1 + e2 + e3;
        uint pref = cnt;
#pragma unroll
        for (int off = 1; off < 64; off <<= 1) {
            uint u = __shfl_up(pref, off, 64);
            if (lane >= off) pref += u;
        }
        if (lane == 63) wtot[wave] = pref;
        __syncthreads();
        uint before = 0, total = 0;
#pragma unroll
        for (int w = 0; w < 16; w++) {
            uint t = wtot[w];
            if (w < wave) before += t;
            total += t;
        }
        uint offs = runningEq + before + (pref - cnt);
        uint local = 0;
        uchar sv[4];
        {
            uint k = key[c][0];
            uchar s = 0;
            if ((base + 0) < N0) {
                if (k > T) s = 1;
                else if (e0 && (offs + local) < needEq) s = 1;
            }
            local += e0; sv[0] = s;
        }
        {
            uint k = key[c][1];
            uchar s = 0;
            if ((base + 1) < N0) {
                if (k > T) s = 1;
                else if (e1 && (offs + local) < needEq) s = 1;
            }
            local += e1; sv[1] = s;
        }
        {
            uint k = key[c][2];
            uchar s = 0;
            if ((base + 2) < N0) {
                if (k > T) s = 1;
                else if (e2 && (offs + local) < needEq) s = 1;
            }
            local += e2; sv[2] = s;
        }
        {
            uint k = key[c][3];
            uchar s = 0;
            if ((base + 3) < N0) {
                if (k > T) s = 1;
                else if (e3 && (offs + local) < needEq) s = 1;
            }
            local += e3; sv[3] = s;
        }
        if (base + 3 < N0) {
            uint packed = (uint)sv[0] | ((uint)sv[1] << 8) | ((uint)sv[2] << 16) | ((uint)sv[3] << 24);
            *reinterpret_cast<uint*>(sl + base) = packed;
        } else {
#pragma unroll
            for (int j = 0; j < 4; j++) if (base + j < N0) sl[base + j] = sv[j];
        }
        runningEq += total;
        __syncthreads();
    }
}

// ---------- fat kernel: conv2 prep (gdinv2 + xw2) ----------
#define GD2_BLOCKS ((N0 + 255) / 256)   // 68
__global__ void k_conv2pre(const int* rowptr, const int* csr, const uchar* sel,
                           const float* h1, const float* score, const float* W2,
                           float* dinv2, float* xw2) {
    int b = blockIdx.x;
    int tid = threadIdx.x;
    if (b < GD2_BLOCKS) {
        int d = b * 256 + tid;
        if (d >= N0) return;
        float r = 0.f;
        if (sel[d]) {
            int c = 0;
            int beg = rowptr[d], end = rowptr[d + 1];
            for (int e = beg; e < end; e++) c += sel[csr[e]];
            r = rsqrtf(1.f + (float)c);
        }
        dinv2[d] = r;
    } else {
        int gt = (b - GD2_BLOCKS) * 256 + tid;
        int i = gt >> 5, c = gt & 31;
        if (i >= N0) return;
        if (!sel[i]) return;
        float t = tanhf(score[i]);
        const float* row = h1 + (size_t)i * H1C;
        float acc = 0.f;
#pragma unroll
        for (int h = 0; h < H1C; h++) acc += row[h] * W2[h * H2C + c];
        xw2[i * H2C + c] = acc * t;
    }
}

__global__ void k_gath2(const int* rowptr, const int* csr, const uchar* sel,
                        const float* dinv2, const float* xw2, float* acc2) {
    int wid = (blockIdx.x * blockDim.x + threadIdx.x) >> 6;
    int lane = threadIdx.x & 63;
    if (wid >= N0) return;
    int d = wid;
    if (!sel[d]) return;
    int c = lane & 31;
    int beg = rowptr[d], end = rowptr[d + 1];
    float a0 = 0.f, a1 = 0.f;
    int e = beg + (lane >> 5);
    for (; e + 2 < end; e += 4) {   // this half-wave handles e, e+2
        int s0 = csr[e], s1 = csr[e + 2];
        a0 += xw2[(size_t)s0 * H2C + c] * dinv2[s0];
        a1 += xw2[(size_t)s1 * H2C + c] * dinv2[s1];
    }
    if (e < end) {
        int s = csr[e];
        a0 += xw2[(size_t)s * H2C + c] * dinv2[s];
    }
    float acc = a0 + a1;
    acc += __shfl_xor(acc, 32, 64);
    if (lane < 32) acc2[(size_t)d * H2C + c] = acc * dinv2[d];
}

__global__ void k_fin2(const float* acc2, const float* xw2, const float* dinv2,
                       const uchar* sel, const float* b2, float* gmax) {
    __shared__ float m[32];
    int tid = threadIdx.x;
    if (tid < 32) m[tid] = 0.f;
    __syncthreads();
    int i = blockIdx.x * 8 + (tid >> 5);
    int c = tid & 31;
    float v = 0.f;
    if (i < N0 && sel[i]) {
        float di = dinv2[i];
        v = fmaxf(acc2[(size_t)i * H2C + c] + xw2[(size_t)i * H2C + c] * di * di + b2[c], 0.f);
    }
    atomicMax((int*)&m[c], __float_as_int(v));
    __syncthreads();
    if (tid < 32) atomicMax((int*)&gmax[tid], __float_as_int(m[tid]));
}

// ---------- graphs 1..63: h2 + max pool, BOTH layers via MFMA (v4) ----------
#define BPGR 68
__global__ __launch_bounds__(256, 2)
void k_rest_pool(const float* __restrict__ x, const float* __restrict__ score,
                 const uchar* __restrict__ sel,
                 const float* __restrict__ W1, const float* __restrict__ b1,
                 const float* __restrict__ W2, const float* __restrict__ b2,
                 float* gmax) {
    __shared__ __align__(16) short sW2T[H2C * 72];
    __shared__ __align__(16) short h1T[4][16 * 72];
    __shared__ float ltl[256];
    __shared__ float lmk[256];
    __shared__ float m[H2C];
    int tid = threadIdx.x;
    if (tid < H2C) m[tid] = 0.f;
    {   // W2^T bf16 staging: sW2T[c][k], row stride 72 shorts (144B)
        int c = tid >> 3, k0 = (tid & 7) * 8;
#pragma unroll
        for (int k = 0; k < 8; k++)
            sW2T[c * 72 + k0 + k] = f2bf(W2[(k0 + k) * H2C + c]);
    }
    int lane = tid & 63;
    int wv = tid >> 6;
    int g = blockIdx.x / BPGR + 1;
    int wslot = (blockIdx.x % BPGR) * 4 + wv;
    int nbase = wslot * 64;
    {   // per-node tanh / mask for this wave's 64 nodes
        int li = nbase + lane;
        bool inb = li < N0;
        int n = g * N0 + (inb ? li : 0);
        bool valid = inb && sel[(size_t)g * SELP + (inb ? li : 0)];
        ltl[tid] = valid ? tanhf(score[n]) : 0.f;
        lmk[tid] = valid ? 1.f : 0.f;
    }
    __syncthreads();

    int col = lane & 15;
    int q = lane >> 4;
    int kb8 = q * 8;
    int wbase = wv * 64;
    short* hrow = &h1T[wv][0];

    bf16x8 B1a = {0, 0, 0, 0, 0, 0, 0, 0};
    bf16x8 B1b = {0, 0, 0, 0, 0, 0, 0, 0};
    bf16x8 B1c = {0, 0, 0, 0, 0, 0, 0, 0};
    bf16x8 B1d = {0, 0, 0, 0, 0, 0, 0, 0};
    if (q == 0) {
#pragma unroll
        for (int j = 0; j < 6; j++) {
            B1a[j] = f2bf(W1[j * H1C + col]);
            B1b[j] = f2bf(W1[j * H1C + 16 + col]);
            B1c[j] = f2bf(W1[j * H1C + 32 + col]);
            B1d[j] = f2bf(W1[j * H1C + 48 + col]);
        }
        B1a[6] = f2bf(b1[col]);
        B1b[6] = f2bf(b1[16 + col]);
        B1c[6] = f2bf(b1[32 + col]);
        B1d[6] = f2bf(b1[48 + col]);
    }
    float b2c0 = b2[col], b2c1 = b2[col + 16];

    float rm0 = 0.f, rm1 = 0.f;
#pragma unroll 1
    for (int grp = 0; grp < 4; grp++) {
        bf16x8 A0 = {0, 0, 0, 0, 0, 0, 0, 0};
        if (q == 0) {
            float tlc = ltl[wbase + grp * 16 + col];
            if (tlc != 0.f) {
                int n = g * N0 + nbase + grp * 16 + col;
                const float2* xv = reinterpret_cast<const float2*>(x) + (size_t)n * 3;
                float2 x01 = xv[0], x23 = xv[1], x45 = xv[2];
                A0[0] = f2bf(x01.x); A0[1] = f2bf(x01.y);
                A0[2] = f2bf(x23.x); A0[3] = f2bf(x23.y);
                A0[4] = f2bf(x45.x); A0[5] = f2bf(x45.y);
            }
            A0[6] = f2bf(1.0f);
        }
        float tn0 = ltl[wbase + grp * 16 + q * 4 + 0];
        float tn1 = ltl[wbase + grp * 16 + q * 4 + 1];
        float tn2 = ltl[wbase + grp * 16 + q * 4 + 2];
        float tn3 = ltl[wbase + grp * 16 + q * 4 + 3];
        {
            f32x4 hz = {0.f, 0.f, 0.f, 0.f};
            f32x4 h = __builtin_amdgcn_mfma_f32_16x16x32_bf16(A0, B1a, hz, 0, 0, 0);
            hrow[(q * 4 + 0) * 72 + col]      = f2bf(tn0 * fmaxf(h[0], 0.f));
            hrow[(q * 4 + 1) * 72 + col]      = f2bf(tn1 * fmaxf(h[1], 0.f));
            hrow[(q * 4 + 2) * 72 + col]      = f2bf(tn2 * fmaxf(h[2], 0.f));
            hrow[(q * 4 + 3) * 72 + col]      = f2bf(tn3 * fmaxf(h[3], 0.f));
            h = __builtin_amdgcn_mfma_f32_16x16x32_bf16(A0, B1b, hz, 0, 0, 0);
            hrow[(q * 4 + 0) * 72 + 16 + col] = f2bf(tn0 * fmaxf(h[0], 0.f));
            hrow[(q * 4 + 1) * 72 + 16 + col] = f2bf(tn1 * fmaxf(h[1], 0.f));
            hrow[(q * 4 + 2) * 72 + 16 + col] = f2bf(tn2 * fmaxf(h[2], 0.f));
            hrow[(q * 4 + 3) * 72 + 16 + col] = f2bf(tn3 * fmaxf(h[3], 0.f));
            h = __builtin_amdgcn_mfma_f32_16x16x32_bf16(A0, B1c, hz, 0, 0, 0);
            hrow[(q * 4 + 0) * 72 + 32 + col] = f2bf(tn0 * fmaxf(h[0], 0.f));
            hrow[(q * 4 + 1) * 72 + 32 + col] = f2bf(tn1 * fmaxf(h[1], 0.f));
            hrow[(q * 4 + 2) * 72 + 32 + col] = f2bf(tn2 * fmaxf(h[2], 0.f));
            hrow[(q * 4 + 3) * 72 + 32 + col] = f2bf(tn3 * fmaxf(h[3], 0.f));
            h = __builtin_amdgcn_mfma_f32_16x16x32_bf16(A0, B1d, hz, 0, 0, 0);
            hrow[(q * 4 + 0) * 72 + 48 + col] = f2bf(tn0 * fmaxf(h[0], 0.f));
            hrow[(q * 4 + 1) * 72 + 48 + col] = f2bf(tn1 * fmaxf(h[1], 0.f));
            hrow[(q * 4 + 2) * 72 + 48 + col] = f2bf(tn2 * fmaxf(h[2], 0.f));
            hrow[(q * 4 + 3) * 72 + 48 + col] = f2bf(tn3 * fmaxf(h[3], 0.f));
        }
        bf16x8 A2_0 = *reinterpret_cast<const bf16x8*>(&hrow[col * 72 + kb8]);
        bf16x8 A2_1 = *reinterpret_cast<const bf16x8*>(&hrow[col * 72 + 32 + kb8]);
        f32x4 acc0 = {0.f, 0.f, 0.f, 0.f};
        f32x4 acc1 = {0.f, 0.f, 0.f, 0.f};
        acc0 = __builtin_amdgcn_mfma_f32_16x16x32_bf16(
            A2_0, *reinterpret_cast<const bf16x8*>(&sW2T[col * 72 + kb8]), acc0, 0, 0, 0);
        acc0 = __builtin_amdgcn_mfma_f32_16x16x32_bf16(
            A2_1, *reinterpret_cast<const bf16x8*>(&sW2T[col * 72 + 32 + kb8]), acc0, 0, 0, 0);
        acc1 = __builtin_amdgcn_mfma_f32_16x16x32_bf16(
            A2_0, *reinterpret_cast<const bf16x8*>(&sW2T[(col + 16) * 72 + kb8]), acc1, 0, 0, 0);
        acc1 = __builtin_amdgcn_mfma_f32_16x16x32_bf16(
            A2_1, *reinterpret_cast<const bf16x8*>(&sW2T[(col + 16) * 72 + 32 + kb8]), acc1, 0, 0, 0);
        float mk0 = lmk[wbase + grp * 16 + q * 4 + 0];
        float mk1 = lmk[wbase + grp * 16 + q * 4 + 1];
        float mk2 = lmk[wbase + grp * 16 + q * 4 + 2];
        float mk3 = lmk[wbase + grp * 16 + q * 4 + 3];
        rm0 = fmaxf(rm0, mk0 * fmaxf(acc0[0] + b2c0, 0.f));
        rm0 = fmaxf(rm0, mk1 * fmaxf(acc0[1] + b2c0, 0.f));
        rm0 = fmaxf(rm0, mk2 * fmaxf(acc0[2] + b2c0, 0.f));
        rm0 = fmaxf(rm0, mk3 * fmaxf(acc0[3] + b2c0, 0.f));
        rm1 = fmaxf(rm1, mk0 * fmaxf(acc1[0] + b2c1, 0.f));
        rm1 = fmaxf(rm1, mk1 * fmaxf(acc1[1] + b2c1, 0.f));
        rm1 = fmaxf(rm1, mk2 * fmaxf(acc1[2] + b2c1, 0.f));
        rm1 = fmaxf(rm1, mk3 * fmaxf(acc1[3] + b2c1, 0.f));
    }
    rm0 = fmaxf(rm0, __shfl_xor(rm0, 16, 64));
    rm0 = fmaxf(rm0, __shfl_xor(rm0, 32, 64));
    rm1 = fmaxf(rm1, __shfl_xor(rm1, 16, 64));
    rm1 = fmaxf(rm1, __shfl_xor(rm1, 32, 64));
    if (lane < 16) {
        atomicMax((int*)&m[col], __float_as_int(rm0));
        atomicMax((int*)&m[col + 16], __float_as_int(rm1));
    }
    __syncthreads();
    if (tid < H2C) atomicMax((int*)&gmax[g * H2C + tid], __float_as_int(m[tid]));
}

// ---------- readout ----------
__global__ void k_final(const float* gmax, const float* Wf, const float* bf, float* out) {
    int g = threadIdx.x;
    if (g < BATCH) {
        float acc = bf[0];
        for (int c = 0; c < H2C; c++) acc += gmax[g * H2C + c] * Wf[c];
        out[g] = 1.f / (1.f + expf(-acc));
    }
}

extern "C" void kernel_launch(void* const* d_in, const int* in_sizes, int n_in,
                              void* d_out, int out_size, void* d_ws, size_t ws_size,
                              hipStream_t stream) {
    const float* data = (const float*)d_in[0];
    const void*  ei   = d_in[1];
    const float* W1   = (const float*)d_in[2];
    const float* b1   = (const float*)d_in[3];
    const float* Wp   = (const float*)d_in[4];
    const float* bp   = (const float*)d_in[5];
    const float* W2   = (const float*)d_in[6];
    const float* b2   = (const float*)d_in[7];
    const float* Wf   = (const float*)d_in[8];
    const float* bf   = (const float*)d_in[9];
    float* out = (float*)d_out;

    char* ws = (char*)d_ws;
    size_t off = 0;
    auto A = [&](size_t bytes) -> size_t {
        size_t o = off; off += (bytes + 511) & ~(size_t)511; return o;
    };
    // zero-initialized region (single memset)
    size_t o_deg0 = A((size_t)N0 * 4);
    size_t o_cnt  = A((size_t)N0 * 4);
    size_t o_gmax = A((size_t)BATCH * H2C * 4);
    size_t zbytes = off;
    // rest
    size_t o_src  = A((size_t)NE * 4);
    size_t o_dst  = A((size_t)NE * 4);
    size_t o_rp   = A((size_t)(N0 + 1) * 4);
    size_t o_csr  = A((size_t)NE * 4);
    size_t o_xw1  = A((size_t)N0 * H1C * 4);
    size_t o_h1   = A((size_t)N0 * H1C * 4);
    size_t o_di0  = A((size_t)N0 * 4);
    size_t o_di2  = A((size_t)N0 * 4);
    size_t o_h1w  = A((size_t)N0 * 4);
    size_t o_hp   = A((size_t)N0 * 4);
    size_t o_scr  = A((size_t)NT * 4);
    size_t o_sel  = A((size_t)BATCH * SELP);
    size_t o_xw2  = A((size_t)N0 * H2C * 4);
    size_t o_acc2 = A((size_t)N0 * H2C * 4);

    uint*  deg0 = (uint*)(ws + o_deg0);
    uint*  cnt  = (uint*)(ws + o_cnt);
    float* gmax = (float*)(ws + o_gmax);
    int*   src  = (int*)(ws + o_src);
    int*   dst  = (int*)(ws + o_dst);
    int*   rp   = (int*)(ws + o_rp);
    int*   csr  = (int*)(ws + o_csr);
    float* xw1  = (float*)(ws + o_xw1);
    float* h1   = (float*)(ws + o_h1);
    float* di0  = (float*)(ws + o_di0);
    float* di2  = (float*)(ws + o_di2);
    float* h1w  = (float*)(ws + o_h1w);
    float* hp   = (float*)(ws + o_hp);
    float* scr  = (float*)(ws + o_scr);
    uchar* sel  = (uchar*)(ws + o_sel);
    float* xw2  = (float*)(ws + o_xw2);
    float* acc2 = (float*)(ws + o_acc2);

    hipMemsetAsync(ws, 0, zbytes, stream);

    k_convert<<<2048, 256, 0, stream>>>(ei, src, dst, deg0);
    {
        int fblocks = XW1_BLOCKS + (NT - N0 + 255) / 256;   // 4297 + 4231
        k_feat<<<fblocks, 256, 0, stream>>>(data, W1, b1, Wp, bp, xw1, scr);
    }
    k_scan<<<1, 256, 0, stream>>>(deg0, rp, di0);
    k_scatter<<<(NE + 255) / 256, 256, 0, stream>>>(src, dst, rp, cnt, csr);
    k_gath1<<<(N0 * 64 + 255) / 256, 256, 0, stream>>>(rp, csr, di0, xw1, b1, Wp, h1, h1w, hp);
    k_gscore0<<<(N0 + 255) / 256, 256, 0, stream>>>(rp, csr, di0, hp, h1w, bp, scr);
    k_topk<<<BATCH, 1024, 0, stream>>>(scr, sel);
    {
        int cblocks = GD2_BLOCKS + (N0 * H2C + 255) / 256;  // 68 + 2149
        k_conv2pre<<<cblocks, 256, 0, stream>>>(rp, csr, sel, h1, scr, W2, di2, xw2);
    }
    k_gath2<<<(N0 * 64 + 255) / 256, 256, 0, stream>>>(rp, csr, sel, di2, xw2, acc2);
    k_fin2<<<(N0 + 7) / 8, 256, 0, stream>>>(acc2, xw2, di2, sel, b2, gmax);
    k_rest_pool<<<(BATCH - 1) * BPGR, 256, 0, stream>>>(data, scr, sel, W1, b1, W2, b2, gmax);
    k_final<<<1, 64, 0, stream>>>(gmax, Wf, bf, out);
}